// Round 19
// baseline (972.764 us; speedup 1.0000x reference)
//
#include <hip/hip_runtime.h>
#include <stdint.h>

// ---------------------------------------------------------------------------
// Block_6554120094246: dual-stream transformer block (CLIP + video streams).
// f32 in/out. Residual streams in d_out. bf16 intermediates.
// R18 schedule (900us) + t2s_kv||s2t_q merged into one 256-tile dual launch
// (fills the 15% tail round). MFMA flash attention v5.
// ---------------------------------------------------------------------------

typedef uint16_t u16;
typedef uint16_t u16x8 __attribute__((ext_vector_type(8)));
typedef uint16_t u16x4 __attribute__((ext_vector_type(4)));
typedef short bf16x8 __attribute__((ext_vector_type(8)));
typedef float f32x4 __attribute__((ext_vector_type(4)));

__device__ __forceinline__ float b2f(u16 u) {
    union { float f; uint32_t i; } x;
    x.i = ((uint32_t)u) << 16;
    return x.f;
}
__device__ __forceinline__ u16 f2b(float f) {
    union { float f; uint32_t i; } x;
    x.f = f;
    uint32_t i = x.i;
    uint32_t r = (i + 0x7FFFu + ((i >> 16) & 1u)) >> 16;  // RNE
    return (u16)r;
}
__device__ __forceinline__ u16 f2b_trunc(float f) {      // for P in [0,256]
    union { float f; uint32_t i; } x;
    x.f = f;
    return (u16)(x.i >> 16);
}

// async global->LDS, 16B per lane; LDS dest wave-uniform base (+lane*16B).
__device__ __forceinline__ void gload16(const u16* g, u16* l) {
    __builtin_amdgcn_global_load_lds(
        (const __attribute__((address_space(1))) uint32_t*)g,
        (__attribute__((address_space(3))) uint32_t*)l, 16, 0, 0);
}

// ---- mega weight convert (one launch, 14 segments) --------------------------
struct CvtAll {
    const float* s[14];
    u16* d[14];
    int cum[15];
};
__global__ __launch_bounds__(256) void cvt_all(CvtAll c) {
    int i = blockIdx.x * 256 + threadIdx.x;
    if (i >= c.cum[14]) return;
    int seg = 0;
    #pragma unroll
    for (int k = 1; k < 14; k++) seg += (i >= c.cum[k]);
    int j = i - c.cum[seg];
    c.d[seg][j] = f2b(c.s[seg][j]);
}

// ---- bias pool ---------------------------------------------------------------
__global__ __launch_bounds__(256) void build_bias_pool(float* __restrict__ dst,
    const float* mha_b, const float* attn_q_b, const float* attn_v_b,
    const float* mha_ob, const float* attn_pb, const float* t2s_kvb,
    const float* t2s_qb, const float* t2s_pb, const float* s2t_qb,
    const float* s2t_kvb, const float* s2t_pb, const float* cfc_b,
    const float* cproj_b, const float* fc1_b, const float* fc2_b) {
    int i = blockIdx.x * 256 + threadIdx.x;
    float v = 0.f;
    if (i < 2304) v = mha_b[i];
    else if (i < 4608) { int j = i - 2304; v = (j < 768) ? attn_q_b[j] : (j < 1536 ? 0.f : attn_v_b[j - 1536]); }
    else if (i < 5376) v = mha_ob[i - 4608];
    else if (i < 6144) v = attn_pb[i - 5376];
    else if (i < 7680) { int j = i - 6144; v = (j < 768) ? 0.f : t2s_kvb[j - 768]; }
    else if (i < 8448) v = t2s_qb[i - 7680];
    else if (i < 9216) v = t2s_pb[i - 8448];
    else if (i < 9984) v = s2t_qb[i - 9216];
    else if (i < 11520) { int j = i - 9984; v = (j < 768) ? 0.f : s2t_kvb[j - 768]; }
    else if (i < 12288) v = s2t_pb[i - 11520];
    else if (i < 15360) v = cfc_b[i - 12288];
    else if (i < 16128) v = cproj_b[i - 15360];
    else if (i < 19200) v = fc1_b[i - 16128];
    else if (i < 19968) v = fc2_b[i - 19200];
    else return;
    dst[i] = v;
}

// ---- block reductions --------------------------------------------------------
__device__ __forceinline__ float block_sum(float v, float* red) {
    #pragma unroll
    for (int o = 32; o > 0; o >>= 1) v += __shfl_down(v, o, 64);
    int w = threadIdx.x >> 6, l = threadIdx.x & 63;
    __syncthreads();
    if (l == 0) red[w] = v;
    __syncthreads();
    return red[0] + red[1] + red[2] + red[3];
}

// ---- LN core -----------------------------------------------------------------
__device__ __forceinline__ void ln_row(const float* xr, const float* g,
                                       const float* bta, u16* yr, float* red) {
    const int t = threadIdx.x;
    float v0 = xr[t], v1 = xr[t + 256], v2 = xr[t + 512];
    float mean = block_sum(v0 + v1 + v2, red) * (1.0f / 768.0f);
    float d0 = v0 - mean, d1 = v1 - mean, d2 = v2 - mean;
    float var = block_sum(d0 * d0 + d1 * d1 + d2 * d2, red) * (1.0f / 768.0f);
    float rs = rsqrtf(var + 1e-5f);
    yr[t]       = f2b(d0 * rs * g[t]       + bta[t]);
    yr[t + 256] = f2b(d1 * rs * g[t + 256] + bta[t + 256]);
    yr[t + 512] = f2b(d2 * rs * g[t + 512] + bta[t + 512]);
}

__global__ __launch_bounds__(256) void ln_dual(
    const float* __restrict__ x, int rows0,
    const float* g0, const float* b0, u16* y0,
    const float* g1, const float* b1, u16* y1) {
    __shared__ float red[4];
    int r = blockIdx.x;
    if (r < rows0) ln_row(x + (size_t)r * 768, g0, b0, y0 + (size_t)r * 768, red);
    else ln_row(x + (size_t)r * 768, g1, b1, y1 + (size_t)(r - rows0) * 768, red);
}

__global__ __launch_bounds__(256) void ln_dual_in(
    const float* __restrict__ xs, const float* __restrict__ xt,
    float* __restrict__ xcopy, int rows0,
    const float* g0, const float* b0, u16* y0,
    const float* g1, const float* b1, u16* y1) {
    __shared__ float red[4];
    int r = blockIdx.x, t = threadIdx.x;
    const float* xr; const float* g; const float* bta; u16* yr;
    if (r < rows0) { xr = xs + (size_t)r * 768; g = g0; bta = b0; yr = y0 + (size_t)r * 768; }
    else { xr = xt + (size_t)(r - rows0) * 768; g = g1; bta = b1; yr = y1 + (size_t)(r - rows0) * 768; }
    float v0 = xr[t], v1 = xr[t + 256], v2 = xr[t + 512];
    float* xc = xcopy + (size_t)r * 768;
    xc[t] = v0; xc[t + 256] = v1; xc[t + 512] = v2;
    float mean = block_sum(v0 + v1 + v2, red) * (1.0f / 768.0f);
    float d0 = v0 - mean, d1 = v1 - mean, d2 = v2 - mean;
    float var = block_sum(d0 * d0 + d1 * d1 + d2 * d2, red) * (1.0f / 768.0f);
    float rs = rsqrtf(var + 1e-5f);
    yr[t]       = f2b(d0 * rs * g[t]       + bta[t]);
    yr[t + 256] = f2b(d1 * rs * g[t + 256] + bta[t + 256]);
    yr[t + 512] = f2b(d2 * rs * g[t + 512] + bta[t + 512]);
}

// ---- V transpose (pairable) ---------------------------------------------------
struct TransP {
    const u16* vp; u16* vt;
    int Nk, Nkp, gx, nb;
    long long vA, vJ;
};
__device__ __forceinline__ void transpose_body(const TransP p, int bid, u16 (*T)[72]) {
    const int x = bid % p.gx, inst = bid / p.gx;
    const int a = inst / 12, h = inst % 12;
    const int t0 = x * 64;
    const int tid = threadIdx.x;
    const int kvl = tid >> 2, dseg = (tid & 3) * 16;
    u16x8 v0 = {}, v1 = {};
    if (t0 + kvl < p.Nk) {
        const u16* src = p.vp + a * p.vA + (long long)(t0 + kvl) * p.vJ + h * 64 + dseg;
        v0 = *(const u16x8*)src;
        v1 = *(const u16x8*)(src + 8);
    }
    *(u16x8*)&T[kvl][dseg]     = v0;
    *(u16x8*)&T[kvl][dseg + 8] = v1;
    __syncthreads();
    const int dl = tid >> 2, kseg = (tid & 3) * 16;
    u16x8 w0, w1;
    #pragma unroll
    for (int j = 0; j < 8; j++) w0[j] = T[kseg + j][dl];
    #pragma unroll
    for (int j = 0; j < 8; j++) w1[j] = T[kseg + 8 + j][dl];
    u16* orow = p.vt + ((size_t)inst * 64 + dl) * p.Nkp + t0 + kseg;
    *(u16x8*)orow = w0;
    *(u16x8*)(orow + 8) = w1;
}
__global__ __launch_bounds__(256) void transpose_pair(TransP p0, TransP p1) {
    __shared__ u16 T[64][72];
    int bid = blockIdx.x;
    if (bid < p0.nb) transpose_body(p0, bid, T);
    else transpose_body(p1, bid - p0.nb, T);
}

// ---- GEMM problem descriptor ---------------------------------------------------
struct GemmP {
    const u16* A; const u16* W; const float* bias;
    u16* Cb; float* Cf;
    int M, N, K, gx, nb;
};

// ---- 128-tile MFMA GEMM body (pairable) ---------------------------------------
template <int MODE, int BM>
__device__ __forceinline__ void gemm_body(const GemmP p, int bid,
                                          u16 (*AsF)[32], u16 (*BsF)[32]) {
    constexpr int MI = BM / 32;
    const int tid = threadIdx.x;
    const int lane = tid & 63;
    const int wid = tid >> 6;
    const int wr = (wid >> 1) * (BM / 2), wc = (wid & 1) * 64;
    const int bx = bid % p.gx, by = bid / p.gx;
    const int m0 = bx * BM, n0 = by * 128;
    const int lr = lane >> 2, lc = (lane & 3) * 8;
    const int fr = lane & 15, fk = (lane >> 4) * 8;
    const int abase = wid * (BM / 4);
    const int bbase = wid * 32;
    f32x4 acc[MI][4] = {};
    for (int k0 = 0; k0 < p.K; k0 += 64) {
        #pragma unroll
        for (int s = 0; s < 2; s++) {
            #pragma unroll
            for (int j = 0; j < BM / 64; j++) {
                int rowa = m0 + abase + j * 16 + lr;
                rowa = rowa < p.M ? rowa : p.M - 1;
                gload16(p.A + (size_t)rowa * p.K + k0 + s * 32 + lc,
                        &AsF[s * 128 + abase + j * 16][0]);
            }
            #pragma unroll
            for (int j = 0; j < 2; j++) {
                gload16(p.W + (size_t)(n0 + bbase + j * 16 + lr) * p.K + k0 + s * 32 + lc,
                        &BsF[s * 128 + bbase + j * 16][0]);
            }
        }
        __syncthreads();
        #pragma unroll
        for (int s = 0; s < 2; s++) {
            bf16x8 a[MI], b[4];
            #pragma unroll
            for (int i = 0; i < MI; i++) a[i] = *(const bf16x8*)&AsF[s * 128 + wr + i * 16 + fr][fk];
            #pragma unroll
            for (int j = 0; j < 4; j++) b[j] = *(const bf16x8*)&BsF[s * 128 + wc + j * 16 + fr][fk];
            #pragma unroll
            for (int i = 0; i < MI; i++)
                #pragma unroll
                for (int j = 0; j < 4; j++)
                    acc[i][j] = __builtin_amdgcn_mfma_f32_16x16x32_bf16(a[i], b[j], acc[i][j], 0, 0, 0);
        }
        __syncthreads();
    }
    const int er = (lane >> 4) * 4;
    #pragma unroll
    for (int i = 0; i < MI; i++) {
        #pragma unroll
        for (int reg = 0; reg < 4; reg++) {
            int r = m0 + wr + i * 16 + er + reg;
            if (r >= p.M) continue;
            #pragma unroll
            for (int j = 0; j < 4; j++) {
                int c = n0 + wc + j * 16 + fr;
                float v = acc[i][j][reg] + p.bias[c];
                size_t idx = (size_t)r * p.N + c;
                if (MODE == 1) {
                    p.Cf[idx] += v;
                } else if (MODE == 4) {
                    float nv = p.Cf[idx] + v;
                    p.Cf[idx] = nv;
                    p.Cb[idx] = f2b(nv);
                } else {
                    if (MODE == 2) v = v / (1.0f + expf(-1.702f * v));
                    if (MODE == 3) v = 0.5f * v * (1.0f + erff(v * 0.70710678118654752f));
                    p.Cb[idx] = f2b(v);
                }
            }
        }
    }
}
template <int M0, int B0, int M1, int B1>
__global__ __launch_bounds__(256) void gemm_pair(GemmP p0, GemmP p1) {
    __shared__ u16 As[2 * 128][32];
    __shared__ u16 Bs[2 * 128][32];
    int bid = blockIdx.x;
    if (bid < p0.nb) gemm_body<M0, B0>(p0, bid, As, Bs);
    else gemm_body<M1, B1>(p1, bid - p0.nb, As, Bs);
}
template <int M0, int B0, int M1, int B1>
__global__ __launch_bounds__(256) void gemm2_trans(GemmP p0, GemmP p1, TransP t0) {
    __shared__ u16 As[2 * 128][32];
    __shared__ u16 Bs[2 * 128][32];
    int bid = blockIdx.x;
    if (bid < p0.nb) gemm_body<M0, B0>(p0, bid, As, Bs);
    else if (bid < p0.nb + p1.nb) gemm_body<M1, B1>(p1, bid - p0.nb, As, Bs);
    else transpose_body(t0, bid - p0.nb - p1.nb, (u16(*)[72])&As[0][0]);
}

// ---- 256x256x64 8-wave GEMM body (M-guarded; T2 swizzle + counted vmcnt) -----
template <int MODE>
__device__ __forceinline__ void g256_body(const GemmP p, int bid, u16* LA, u16* LB) {
    const int tid = threadIdx.x;
    const int lane = tid & 63, wid = tid >> 6;
    const int wm = wid >> 2, wn = wid & 3;
    const int bx = bid % p.gx, by = bid / p.gx;
    const int m0 = bx * 256, n0 = by * 256;
    const int srow = tid >> 3;
    const int sgcol = ((tid & 7) * 8) ^ (((tid >> 3) & 7) << 3);
    const int K = p.K, M = p.M;
    const u16* Ag = p.A;
    const u16* Bg = p.W + (size_t)n0 * K;
    const int fr = lane & 15, g = lane >> 4, fk = g * 8;
    const int rsw = (fr & 7) << 3;

    auto stage1 = [&](int s, int kc, int which) {
        if (which < 2) {
            #pragma unroll
            for (int c = 0; c < 2; c++) {
                int rl = which * 128 + c * 64 + srow;
                gload16(Bg + (size_t)rl * K + kc + sgcol,
                        LB + s * 16384 + which * 8192 + c * 4096 + wid * 512);
            }
        } else {
            int hf = which - 2;
            #pragma unroll
            for (int c = 0; c < 2; c++) {
                int rg = m0 + hf * 128 + c * 64 + srow;
                rg = rg < M ? rg : M - 1;
                gload16(Ag + (size_t)rg * K + kc + sgcol,
                        LA + s * 16384 + hf * 8192 + c * 4096 + wid * 512);
            }
        }
    };

    f32x4 acc[8][4] = {};
    const int NT = K >> 6;
    stage1(0, 0, 0); stage1(0, 0, 1); stage1(0, 0, 2); stage1(0, 0, 3);

    for (int kt = 0; kt < NT; kt++) {
        const int cur = kt & 1;
        const int kn = (kt + 1) << 6;
        const bool pf = (kt + 1 < NT);
        asm volatile("s_waitcnt vmcnt(2)" ::: "memory");
        __builtin_amdgcn_s_barrier();
        bf16x8 bfr[4][2];
        #pragma unroll
        for (int fj = 0; fj < 4; fj++)
            #pragma unroll
            for (int ks = 0; ks < 2; ks++)
                bfr[fj][ks] = *(const bf16x8*)&LB[cur * 16384 + (wn * 64 + fj * 16 + fr) * 64 + ((ks * 32 + fk) ^ rsw)];
        #pragma unroll
        for (int ph = 0; ph < 2; ph++) {
            bf16x8 afr[2][2];
            #pragma unroll
            for (int i2 = 0; i2 < 2; i2++)
                #pragma unroll
                for (int ks = 0; ks < 2; ks++)
                    afr[i2][ks] = *(const bf16x8*)&LA[cur * 16384 + ((ph * 2 + i2) * 32 + wm * 16 + fr) * 64 + ((ks * 32 + fk) ^ rsw)];
            if (pf) stage1(cur ^ 1, kn, ph);
            __builtin_amdgcn_s_setprio(1);
            #pragma unroll
            for (int i2 = 0; i2 < 2; i2++)
                #pragma unroll
                for (int ks = 0; ks < 2; ks++)
                    #pragma unroll
                    for (int fj = 0; fj < 4; fj++)
                        acc[ph * 2 + i2][fj] = __builtin_amdgcn_mfma_f32_16x16x32_bf16(
                            afr[i2][ks], bfr[fj][ks], acc[ph * 2 + i2][fj], 0, 0, 0);
            __builtin_amdgcn_s_setprio(0);
        }
        if (pf) asm volatile("s_waitcnt vmcnt(4)" ::: "memory");
        else    asm volatile("s_waitcnt vmcnt(0)" ::: "memory");
        __builtin_amdgcn_s_barrier();
        #pragma unroll
        for (int ph = 2; ph < 4; ph++) {
            bf16x8 afr[2][2];
            #pragma unroll
            for (int i2 = 0; i2 < 2; i2++)
                #pragma unroll
                for (int ks = 0; ks < 2; ks++)
                    afr[i2][ks] = *(const bf16x8*)&LA[cur * 16384 + ((ph * 2 + i2) * 32 + wm * 16 + fr) * 64 + ((ks * 32 + fk) ^ rsw)];
            if (pf) stage1(cur ^ 1, kn, ph);
            __builtin_amdgcn_s_setprio(1);
            #pragma unroll
            for (int i2 = 0; i2 < 2; i2++)
                #pragma unroll
                for (int ks = 0; ks < 2; ks++)
                    #pragma unroll
                    for (int fj = 0; fj < 4; fj++)
                        acc[ph * 2 + i2][fj] = __builtin_amdgcn_mfma_f32_16x16x32_bf16(
                            afr[i2][ks], bfr[fj][ks], acc[ph * 2 + i2][fj], 0, 0, 0);
            __builtin_amdgcn_s_setprio(0);
        }
    }
    const int er = g * 4;
    #pragma unroll
    for (int fi = 0; fi < 8; fi++) {
        #pragma unroll
        for (int reg = 0; reg < 4; reg++) {
            int rr = m0 + fi * 32 + wm * 16 + er + reg;
            if (rr >= M) continue;
            #pragma unroll
            for (int fj = 0; fj < 4; fj++) {
                int c = n0 + wn * 64 + fj * 16 + fr;
                float v = acc[fi][fj][reg] + p.bias[c];
                size_t idx = (size_t)rr * p.N + c;
                if (MODE == 1) {
                    p.Cf[idx] += v;
                } else if (MODE == 4) {
                    float nv = p.Cf[idx] + v;
                    p.Cf[idx] = nv;
                    p.Cb[idx] = f2b(nv);
                } else {
                    if (MODE == 2) v = v / (1.0f + expf(-1.702f * v));
                    if (MODE == 3) v = 0.5f * v * (1.0f + erff(v * 0.70710678118654752f));
                    p.Cb[idx] = f2b(v);
                }
            }
        }
    }
}
template <int M0, int M1>
__global__ __launch_bounds__(512) void gemm256_dual(GemmP p0, GemmP p1) {
    __shared__ u16 LA[2 * 256 * 64];
    __shared__ u16 LB[2 * 256 * 64];
    int nwg = gridDim.x;
    int q = nwg >> 3, r8 = nwg & 7;
    int xcd = blockIdx.x & 7, orig = blockIdx.x >> 3;
    int bid = (xcd < r8 ? xcd * (q + 1) : r8 * (q + 1) + (xcd - r8) * q) + orig;
    if (bid < p0.nb) g256_body<M0>(p0, bid, LA, LB);
    else g256_body<M1>(p1, bid - p0.nb, LA, LB);
}

// ---- MFMA flash attention v5 --------------------------------------------------
struct FlashP {
    const u16* qp; const u16* kp; const u16* vt; u16* op;
    int Nq, Nk, Nkp, gx, nb;
    long long qA, qI, kA, kJ, oA, oI;
};
__device__ __forceinline__ void flash_body(const FlashP p, int bid,
    u16 (*Ks)[64][64], u16 (*Vs)[64][64], u16 (*Ps)[16][64]) {
    const int x = bid % p.gx, inst = bid / p.gx;
    const int a = inst / 12, h = inst % 12;
    const int tid = threadIdx.x, lane = tid & 63, w = tid >> 6;
    const int fr = lane & 15, g = lane >> 4, fk = g * 8;
    const int f3s = (fr & 7) << 3;
    const u16* qb = p.qp + a * p.qA + h * 64;
    const u16* kb = p.kp + a * p.kA + h * 64;
    const u16* vtb = p.vt + (size_t)inst * 64 * p.Nkp;
    const int q0 = x * 64 + w * 16;

    bf16x8 qf[2];
    {
        u16x8 raw0 = {}, raw1 = {};
        int qr = q0 + fr;
        if (qr < p.Nq) {
            const u16* qrp = qb + (long long)qr * p.qI;
            raw0 = *(const u16x8*)(qrp + fk);
            raw1 = *(const u16x8*)(qrp + 32 + fk);
        }
        const float QS = 0.125f * 1.44269504088896340736f;
        u16x8 s0, s1;
        #pragma unroll
        for (int e = 0; e < 8; e++) {
            s0[e] = f2b(b2f(raw0[e]) * QS);
            s1[e] = f2b(b2f(raw1[e]) * QS);
        }
        qf[0] = *(bf16x8*)&s0;
        qf[1] = *(bf16x8*)&s1;
    }
    float mrun = -1e30f, lrun = 0.f;
    f32x4 o[4] = {};

    const int l = lane;
    const int srow = w * 8 + (l >> 3);
    const int sdcol = ((l & 7) * 8) ^ (((l >> 3) & 7) << 3);

    auto STAGE = [&](int s, int t0) {
        #pragma unroll
        for (int c = 0; c < 2; c++) {
            int row = c * 32 + srow;
            int kr = t0 + row; if (kr >= p.Nk) kr = p.Nk - 1;
            gload16(kb + (long long)kr * p.kJ + sdcol, &Ks[s][0][0] + c * 2048 + w * 512);
            gload16(vtb + (size_t)row * p.Nkp + t0 + sdcol, &Vs[s][0][0] + c * 2048 + w * 512);
        }
    };

    const int nt = (p.Nk + 63) >> 6;
    STAGE(0, 0);
    for (int it = 0; it < nt; ++it) {
        const int t0 = it << 6;
        const int cur = it & 1;
        if (it + 1 < nt) {
            STAGE(cur ^ 1, t0 + 64);
            asm volatile("s_waitcnt vmcnt(4)" ::: "memory");
        } else {
            asm volatile("s_waitcnt vmcnt(0)" ::: "memory");
        }
        __builtin_amdgcn_s_barrier();

        f32x4 s[4] = {};
        __builtin_amdgcn_s_setprio(1);
        #pragma unroll
        for (int hh = 0; hh < 4; hh++) {
            bf16x8 k0f = *(const bf16x8*)&Ks[cur][hh * 16 + fr][fk ^ f3s];
            bf16x8 k1f = *(const bf16x8*)&Ks[cur][hh * 16 + fr][(32 + fk) ^ f3s];
            s[hh] = __builtin_amdgcn_mfma_f32_16x16x32_bf16(k0f, qf[0], s[hh], 0, 0, 0);
            s[hh] = __builtin_amdgcn_mfma_f32_16x16x32_bf16(k1f, qf[1], s[hh], 0, 0, 0);
        }
        __builtin_amdgcn_s_setprio(0);

        if (t0 + 64 > p.Nk) {
            #pragma unroll
            for (int hh = 0; hh < 4; hh++)
                #pragma unroll
                for (int r = 0; r < 4; r++)
                    if (t0 + hh * 16 + 4 * g + r >= p.Nk) s[hh][r] = -1e30f;
        }
        float a0 = fmaxf(fmaxf(s[0][0], s[0][1]), s[0][2]);
        float a1 = fmaxf(fmaxf(s[0][3], s[1][0]), s[1][1]);
        float a2 = fmaxf(fmaxf(s[1][2], s[1][3]), s[2][0]);
        float a3 = fmaxf(fmaxf(s[2][1], s[2][2]), s[2][3]);
        float a4 = fmaxf(fmaxf(s[3][0], s[3][1]), s[3][2]);
        float b0 = fmaxf(fmaxf(a0, a1), a2);
        float b1 = fmaxf(fmaxf(a3, a4), s[3][3]);
        float lmax = fmaxf(b0, b1);
        lmax = fmaxf(lmax, __shfl_xor(lmax, 16, 64));
        lmax = fmaxf(lmax, __shfl_xor(lmax, 32, 64));
        if (!__all(lmax <= mrun + 8.0f)) {
            float mn = fmaxf(mrun, lmax);
            float sf = exp2f(mrun - mn);
            mrun = mn;
            lrun *= sf;
            float sfo[4];
            #pragma unroll
            for (int r = 0; r < 4; r++) sfo[r] = __shfl(sf, g * 4 + r, 64);
            #pragma unroll
            for (int dt = 0; dt < 4; dt++)
                #pragma unroll
                for (int r = 0; r < 4; r++) o[dt][r] *= sfo[r];
        }
        float pp[4][4];
        float ps = 0.f;
        #pragma unroll
        for (int hh = 0; hh < 4; hh++)
            #pragma unroll
            for (int r = 0; r < 4; r++) {
                pp[hh][r] = exp2f(s[hh][r] - mrun);
                ps += pp[hh][r];
            }
        ps += __shfl_xor(ps, 16, 64);
        ps += __shfl_xor(ps, 32, 64);
        lrun += ps;
        #pragma unroll
        for (int hh = 0; hh < 4; hh++) {
            u16x4 pk;
            #pragma unroll
            for (int r = 0; r < 4; r++) pk[r] = f2b_trunc(pp[hh][r]);
            *(u16x4*)&Ps[w][fr][(hh * 16 + g * 4) ^ f3s] = pk;
        }
        bf16x8 pa0 = *(const bf16x8*)&Ps[w][fr][fk ^ f3s];
        bf16x8 pa1 = *(const bf16x8*)&Ps[w][fr][(32 + fk) ^ f3s];
        __builtin_amdgcn_s_setprio(1);
        #pragma unroll
        for (int dt = 0; dt < 4; dt++) {
            bf16x8 vf0 = *(const bf16x8*)&Vs[cur][dt * 16 + fr][fk ^ f3s];
            bf16x8 vf1 = *(const bf16x8*)&Vs[cur][dt * 16 + fr][(32 + fk) ^ f3s];
            o[dt] = __builtin_amdgcn_mfma_f32_16x16x32_bf16(pa0, vf0, o[dt], 0, 0, 0);
            o[dt] = __builtin_amdgcn_mfma_f32_16x16x32_bf16(pa1, vf1, o[dt], 0, 0, 0);
        }
        __builtin_amdgcn_s_setprio(0);
        __builtin_amdgcn_s_barrier();
    }
    float rcp = 1.0f / lrun;
    #pragma unroll
    for (int r = 0; r < 4; r++) {
        float rr = __shfl(rcp, g * 4 + r, 64);
        int qq = q0 + g * 4 + r;
        if (qq >= p.Nq) continue;
        u16* orow = p.op + a * p.oA + (long long)qq * p.oI + h * 64;
        #pragma unroll
        for (int dt = 0; dt < 4; dt++)
            orow[dt * 16 + fr] = f2b(o[dt][r] * rr);
    }
}
__global__ __launch_bounds__(256) void flash_pair(FlashP p0, FlashP p1) {
    __shared__ u16 Ks[2][64][64];
    __shared__ u16 Vs[2][64][64];
    __shared__ u16 Ps[4][16][64];
    int bid = blockIdx.x;
    if (bid < p0.nb) flash_body(p0, bid, Ks, Vs, Ps);
    else flash_body(p1, bid - p0.nb, Ks, Vs, Ps);
}

// ---------------------------------------------------------------------------
extern "C" void kernel_launch(void* const* d_in, const int* in_sizes, int n_in,
                              void* d_out, int out_size, void* d_ws, size_t ws_size,
                              hipStream_t stream) {
    const int B = 8, sN = 196, tN = 1568;
    const int Ms = B * sN;            // 1568
    const int Mt = B * tN;            // 12544
    const int n_sf = Ms * 768;
    const int n_tf = Mt * 768;
    (void)n_in; (void)out_size; (void)ws_size;

    const bool dict_order = (in_sizes[0] == n_sf);
    auto IN = [&](int di, int ai) -> const float* {
        return (const float*)d_in[dict_order ? di : ai];
    };
    const float* in_sx      = IN(0, 35);
    const float* in_tx      = IN(1, 42);
    const float* ln1s_g     = IN(2, 14);
    const float* ln1s_b     = IN(3, 13);
    const float* mha_w      = IN(4, 28);
    const float* mha_b      = IN(5, 25);
    const float* mha_ow     = IN(6, 27);
    const float* mha_ob     = IN(7, 26);
    const float* ln1t_g     = IN(8, 16);
    const float* ln1t_b     = IN(9, 15);
    const float* attn_qkv_w = IN(10, 3);
    const float* attn_q_b   = IN(11, 2);
    const float* attn_v_b   = IN(12, 4);
    const float* attn_pw    = IN(13, 1);
    const float* attn_pb    = IN(14, 0);
    const float* lnt2s_g    = IN(15, 24);
    const float* lnt2s_b    = IN(16, 23);
    const float* t2s_qw     = IN(17, 41);
    const float* t2s_qb     = IN(18, 40);
    const float* t2s_kvw    = IN(19, 37);
    const float* t2s_kvb    = IN(20, 36);
    const float* t2s_pw     = IN(21, 39);
    const float* t2s_pb     = IN(22, 38);
    const float* lns2t_g    = IN(23, 22);
    const float* lns2t_b    = IN(24, 21);
    const float* s2t_qw     = IN(25, 34);
    const float* s2t_qb     = IN(26, 33);
    const float* s2t_kvw    = IN(27, 30);
    const float* s2t_kvb    = IN(28, 29);
    const float* s2t_pw     = IN(29, 32);
    const float* s2t_pb     = IN(30, 31);
    const float* ln2s_g     = IN(31, 18);
    const float* ln2s_b     = IN(32, 17);
    const float* cfc_w      = IN(33, 6);
    const float* cfc_b      = IN(34, 5);
    const float* cproj_w    = IN(35, 8);
    const float* cproj_b    = IN(36, 7);
    const float* ln2t_g     = IN(37, 20);
    const float* ln2t_b     = IN(38, 19);
    const float* fc1_w      = IN(39, 10);
    const float* fc1_b      = IN(40, 9);
    const float* fc2_w      = IN(41, 12);
    const float* fc2_b      = IN(42, 11);

    float* s_f = (float*)d_out;
    float* t_f = (float*)d_out + n_sf;

    // ---- workspace ----------------------------------------------------------
    char* ws = (char*)d_ws;
    size_t off = 0;
    auto take = [&](size_t bytes) { size_t o = off; off += (bytes + 255) & ~(size_t)255; return o; };
    float* biasP = (float*)(ws + take(19968 * 4));
    u16*   yb    = (u16*)(ws + take((size_t)(Ms + Mt) * 768 * 2));
    u16*   bufA  = (u16*)(ws + take((size_t)Mt * 3072 * 2));
    u16*   bufS  = (u16*)(ws + take((size_t)Mt * 768 * 2));
    u16*   bufB  = (u16*)(ws + take((size_t)Mt * 768 * 2));
    u16*   sxb   = (u16*)(ws + take((size_t)Ms * 768 * 2));
    u16*   vtb_t = (u16*)(ws + take((size_t)96 * 64 * 1600 * 2));
    u16*   yb_s  = yb;
    u16*   yb_t  = yb + (size_t)Ms * 768;
    u16*   vtb_s = yb;   // alias: live only while yb fully dead (steps 6-7)
    auto wtake = [&](size_t nelem) { return (u16*)(ws + take(nelem * 2)); };
    u16 *W_mha   = wtake(2304 * 768), *W_mhao  = wtake(768 * 768);
    u16 *W_qkv   = wtake(2304 * 768), *W_attnp = wtake(768 * 768);
    u16 *W_t2sq  = wtake(768 * 768),  *W_t2skv = wtake(1536 * 768), *W_t2sp = wtake(768 * 768);
    u16 *W_s2tq  = wtake(768 * 768),  *W_s2tkv = wtake(1536 * 768), *W_s2tp = wtake(768 * 768);
    u16 *W_cfc   = wtake(3072 * 768), *W_cproj = wtake(768 * 3072);
    u16 *W_fc1   = wtake(3072 * 768), *W_fc2   = wtake(768 * 3072);

    const int B_MHA = 0, B_QKV = 2304, B_MHAO = 4608, B_ATTNP = 5376;
    const int B_T2SKV = 6144, B_T2SQ = 7680, B_T2SP = 8448, B_S2TQ = 9216;
    const int B_S2TKV = 9984, B_S2TP = 11520, B_CFC = 12288, B_CPROJ = 15360;
    const int B_FC1 = 16128, B_FC2 = 19200;

    auto cdiv = [](int a, int b) { return (a + b - 1) / b; };

    // 1. weights -> bf16
    {
        CvtAll c;
        const float* ss[14] = { mha_w, mha_ow, attn_qkv_w, attn_pw, t2s_qw, t2s_kvw, t2s_pw,
                                s2t_qw, s2t_kvw, s2t_pw, cfc_w, cproj_w, fc1_w, fc2_w };
        u16* dd[14] = { W_mha, W_mhao, W_qkv, W_attnp, W_t2sq, W_t2skv, W_t2sp,
                        W_s2tq, W_s2tkv, W_s2tp, W_cfc, W_cproj, W_fc1, W_fc2 };
        int nn[14] = { 2304*768, 768*768, 2304*768, 768*768, 768*768, 1536*768, 768*768,
                       768*768, 1536*768, 768*768, 3072*768, 768*3072, 3072*768, 768*3072 };
        int cum = 0;
        for (int k = 0; k < 14; k++) { c.s[k] = ss[k]; c.d[k] = dd[k]; c.cum[k] = cum; cum += nn[k]; }
        c.cum[14] = cum;
        cvt_all<<<cdiv(cum, 256), 256, 0, stream>>>(c);
    }
    // 2. bias pool
    build_bias_pool<<<78, 256, 0, stream>>>(biasP,
        mha_b, attn_q_b, attn_v_b, mha_ob, attn_pb, t2s_kvb, t2s_qb, t2s_pb,
        s2t_qb, s2t_kvb, s2t_pb, cfc_b, cproj_b, fc1_b, fc2_b);

    auto GP = [&](const u16* A, const u16* W, const float* bias, u16* Cb, float* Cf,
                  int M, int N, int K, int BM) {
        GemmP p; p.A = A; p.W = W; p.bias = bias; p.Cb = Cb; p.Cf = Cf;
        p.M = M; p.N = N; p.K = K; p.gx = (M + BM - 1) / BM; p.nb = p.gx * (N / 128);
        return p;
    };
    auto GP256 = [&](const u16* A, const u16* W, const float* bias, u16* Cb, float* Cf,
                     int M, int N, int K) {
        GemmP p; p.A = A; p.W = W; p.bias = bias; p.Cb = Cb; p.Cf = Cf;
        p.M = M; p.N = N; p.K = K; p.gx = (M + 255) / 256; p.nb = p.gx * (N / 256);
        return p;
    };
    auto ZERO = [&](GemmP p) { GemmP z = p; z.nb = 0; return z; };
    auto FPm = [&](const u16* qp, const u16* kp, const u16* vt, u16* op,
                   int Nq, int Nk, int Nkp, int insts,
                   long long qA, long long qI, long long kA, long long kJ,
                   long long oA, long long oI) {
        FlashP p; p.qp = qp; p.kp = kp; p.vt = vt; p.op = op;
        p.Nq = Nq; p.Nk = Nk; p.Nkp = Nkp; p.gx = (Nq + 63) / 64;
        p.nb = p.gx * insts;
        p.qA = qA; p.qI = qI; p.kA = kA; p.kJ = kJ; p.oA = oA; p.oI = oI;
        return p;
    };
    auto TP = [&](const u16* vp, u16* vt, int Nk, int Nkp, long long vA, long long vJ, int insts) {
        TransP p; p.vp = vp; p.vt = vt; p.Nk = Nk; p.Nkp = Nkp;
        p.gx = (Nk + 63) / 64; p.nb = p.gx * insts; p.vA = vA; p.vJ = vJ;
        return p;
    };

    // 3. stream copy + LN1 pair
    ln_dual_in<<<Ms + Mt, 256, 0, stream>>>(in_sx, in_tx, (float*)d_out, Ms,
        ln1s_g, ln1s_b, yb_s, ln1t_g, ln1t_b, yb_t);

    // 4. qkv_t (256-tile, 441 blocks)
    {
        GemmP p0 = GP256(yb_t, W_qkv, biasP + B_QKV, bufA, 0, Mt, 2304, 768);
        gemm256_dual<0, 0><<<p0.nb, 512, 0, stream>>>(p0, ZERO(p0));
    }
    // 5. qkv_s (128-tile BM=64, dense)
    {
        GemmP p0 = GP(yb_s, W_mha, biasP + B_MHA, bufS, 0, Ms, 2304, 768, 64);
        gemm_pair<0, 64, 0, 64><<<p0.nb, 256, 0, stream>>>(p0, ZERO(p0));
    }
    // 6. transpose pair
    {
        TransP p0 = TP(bufS + 1536, vtb_s, 8, 64, 2304LL, (long long)sN * 2304, sN * 12);
        TransP p1 = TP(bufA + 1536, vtb_t, tN, 1600, (long long)tN * 2304, 2304LL, B * 12);
        transpose_pair<<<p0.nb + p1.nb, 256, 0, stream>>>(p0, p1);
    }
    // 7. flash pair (stage1 -> sxb, stage2 -> bufB)
    {
        FlashP p0 = FPm(bufS, bufS + 768, vtb_s, sxb, 8, 8, 64, sN * 12,
                        2304LL, (long long)sN * 2304, 2304LL, (long long)sN * 2304,
                        768LL, (long long)sN * 768);
        FlashP p1 = FPm(bufA, bufA + 768, vtb_t, bufB, tN, tN, 1600, B * 12,
                        (long long)tN * 2304, 2304LL, (long long)tN * 2304, 2304LL,
                        (long long)tN * 768, 768LL);
        flash_pair<<<p0.nb + p1.nb, 256, 0, stream>>>(p0, p1);
    }
    // 8. proj pair (mha MODE1 || attn MODE4 -> t_f + yb_t)
    {
        GemmP p0 = GP(sxb, W_mhao, biasP + B_MHAO, 0, s_f, Ms, 768, 768, 64);
        GemmP p1 = GP(bufB, W_attnp, biasP + B_ATTNP, yb_t, t_f, Mt, 768, 768, 128);
        gemm_pair<1, 64, 4, 128><<<p0.nb + p1.nb, 256, 0, stream>>>(p0, p1);
    }
    // 9. LN pair: lnt2s -> yb_s || lns2t -> bufB
    ln_dual<<<Ms + Mt, 256, 0, stream>>>((const float*)d_out, Ms,
        lnt2s_g, lnt2s_b, yb_s, lns2t_g, lns2t_b, bufB);
    // 10. t2s_kv || s2t_q merged (both t-stream; 294+147=441 blocks, fills tail)
    {
        GemmP p0 = GP256(yb_t, W_t2skv, biasP + B_T2SKV, bufA, 0, Mt, 1536, 768);
        GemmP p1 = GP256(bufB, W_s2tq, biasP + B_S2TQ, bufS, 0, Mt, 768, 768);
        gemm256_dual<0, 0><<<p0.nb + p1.nb, 512, 0, stream>>>(p0, p1);
    }
    // 11. t2s_q (128-tile BM=64) || transpose(t2s V -> vtb_t)
    {
        GemmP p0 = GP(yb_s, W_t2sq, biasP + B_T2SQ, sxb, 0, Ms, 768, 768, 64);
        TransP t0 = TP(bufA + 768, vtb_t, tN, 1600, (long long)tN * 1536, 1536LL, B * 12);
        gemm2_trans<0, 64, 0, 64><<<p0.nb + t0.nb, 256, 0, stream>>>(p0, ZERO(p0), t0);
    }
    // 12. flash stage3 -> yb_s
    {
        FlashP p0 = FPm(sxb, bufA, vtb_t, yb_s, sN, tN, 1600, B * 12,
                        (long long)sN * 768, 768LL, (long long)tN * 1536, 1536LL,
                        (long long)sN * 768, 768LL);
        FlashP pz = p0; pz.nb = 0;
        flash_pair<<<p0.nb, 256, 0, stream>>>(p0, pz);
    }
    // 13. t2s proj (MODE4 -> s_f + sxb mirror)
    {
        GemmP p0 = GP(yb_s, W_t2sp, biasP + B_T2SP, sxb, s_f, Ms, 768, 768, 64);
        gemm_pair<4, 64, 4, 64><<<p0.nb, 256, 0, stream>>>(p0, ZERO(p0));
    }
    // 14. LN ln2s -> yb_s
    ln_dual<<<Ms, 256, 0, stream>>>((const float*)d_out, Ms,
        ln2s_g, ln2s_b, yb_s, ln2s_g, ln2s_b, yb_s);
    // 15. s2t_kv || cfc (QuickGELU -> yb_t)
    {
        GemmP p0 = GP(sxb, W_s2tkv, biasP + B_S2TKV, bufB, 0, Ms, 1536, 768, 64);
        GemmP p1 = GP(yb_s, W_cfc, biasP + B_CFC, yb_t, 0, Ms, 3072, 768, 64);
        gemm_pair<0, 64, 2, 64><<<p0.nb + p1.nb, 256, 0, stream>>>(p0, p1);
    }
    // 16. cproj (MODE1 -> s_f) || transpose(s2t V -> bufA)
    {
        GemmP p0 = GP(yb_t, W_cproj, biasP + B_CPROJ, 0, s_f, Ms, 768, 3072, 64);
        TransP t0 = TP(bufB + 768, bufA, sN, 256, (long long)sN * 1536, 1536LL, B * 12);
        gemm2_trans<1, 64, 1, 64><<<p0.nb + t0.nb, 256, 0, stream>>>(p0, ZERO(p0), t0);
    }
    // 17. flash stage4 -> yb
    {
        FlashP p0 = FPm(bufS, bufB, bufA, yb, tN, sN, 256, B * 12,
                        (long long)tN * 768, 768LL, (long long)sN * 1536, 1536LL,
                        (long long)tN * 768, 768LL);
        FlashP pz = p0; pz.nb = 0;
        flash_pair<<<p0.nb, 256, 0, stream>>>(p0, pz);
    }
    // 18. s2t proj (256-tile, MODE1 -> t_f)
    {
        GemmP p0 = GP256(yb, W_s2tp, biasP + B_S2TP, 0, t_f, Mt, 768, 768);
        gemm256_dual<1, 1><<<p0.nb, 512, 0, stream>>>(p0, ZERO(p0));
    }
    // 19. LN ln2t -> yb_t
    ln_dual<<<Mt, 256, 0, stream>>>(t_f, 0,
        ln2t_g, ln2t_b, yb_t, ln2t_g, ln2t_b, yb_t);
    // 20. fc1 (256-tile, exact GELU -> bufA, 588 blocks)
    {
        GemmP p0 = GP256(yb_t, W_fc1, biasP + B_FC1, bufA, 0, Mt, 3072, 768);
        gemm256_dual<3, 3><<<p0.nb, 512, 0, stream>>>(p0, ZERO(p0));
    }
    // 21. fc2 (256-tile, MODE1 -> t_f, K=3072 deep pipeline)
    {
        GemmP p0 = GP256(bufA, W_fc2, biasP + B_FC2, 0, t_f, Mt, 768, 3072);
        gemm256_dual<1, 1><<<p0.nb, 512, 0, stream>>>(p0, ZERO(p0));
    }
}

// Round 20
// 902.353 us; speedup vs baseline: 1.0780x; 1.0780x over previous
//
#include <hip/hip_runtime.h>
#include <stdint.h>

// ---------------------------------------------------------------------------
// Block_6554120094246: dual-stream transformer block (CLIP + video streams).
// f32 in/out. Residual streams in d_out. bf16 intermediates.
// Schedule = measured-best R18 config (900us): s-stream GEMMs 128-tile/dense;
// qkv_t, t2s_kv, fc1, s2t_proj, fc2 at 256-tile; paired/hetero launches.
// MFMA flash attention v5.
// ---------------------------------------------------------------------------

typedef uint16_t u16;
typedef uint16_t u16x8 __attribute__((ext_vector_type(8)));
typedef uint16_t u16x4 __attribute__((ext_vector_type(4)));
typedef short bf16x8 __attribute__((ext_vector_type(8)));
typedef float f32x4 __attribute__((ext_vector_type(4)));

__device__ __forceinline__ float b2f(u16 u) {
    union { float f; uint32_t i; } x;
    x.i = ((uint32_t)u) << 16;
    return x.f;
}
__device__ __forceinline__ u16 f2b(float f) {
    union { float f; uint32_t i; } x;
    x.f = f;
    uint32_t i = x.i;
    uint32_t r = (i + 0x7FFFu + ((i >> 16) & 1u)) >> 16;  // RNE
    return (u16)r;
}
__device__ __forceinline__ u16 f2b_trunc(float f) {      // for P in [0,256]
    union { float f; uint32_t i; } x;
    x.f = f;
    return (u16)(x.i >> 16);
}

// async global->LDS, 16B per lane; LDS dest wave-uniform base (+lane*16B).
__device__ __forceinline__ void gload16(const u16* g, u16* l) {
    __builtin_amdgcn_global_load_lds(
        (const __attribute__((address_space(1))) uint32_t*)g,
        (__attribute__((address_space(3))) uint32_t*)l, 16, 0, 0);
}

// ---- mega weight convert (one launch, 14 segments) --------------------------
struct CvtAll {
    const float* s[14];
    u16* d[14];
    int cum[15];
};
__global__ __launch_bounds__(256) void cvt_all(CvtAll c) {
    int i = blockIdx.x * 256 + threadIdx.x;
    if (i >= c.cum[14]) return;
    int seg = 0;
    #pragma unroll
    for (int k = 1; k < 14; k++) seg += (i >= c.cum[k]);
    int j = i - c.cum[seg];
    c.d[seg][j] = f2b(c.s[seg][j]);
}

// ---- bias pool ---------------------------------------------------------------
__global__ __launch_bounds__(256) void build_bias_pool(float* __restrict__ dst,
    const float* mha_b, const float* attn_q_b, const float* attn_v_b,
    const float* mha_ob, const float* attn_pb, const float* t2s_kvb,
    const float* t2s_qb, const float* t2s_pb, const float* s2t_qb,
    const float* s2t_kvb, const float* s2t_pb, const float* cfc_b,
    const float* cproj_b, const float* fc1_b, const float* fc2_b) {
    int i = blockIdx.x * 256 + threadIdx.x;
    float v = 0.f;
    if (i < 2304) v = mha_b[i];
    else if (i < 4608) { int j = i - 2304; v = (j < 768) ? attn_q_b[j] : (j < 1536 ? 0.f : attn_v_b[j - 1536]); }
    else if (i < 5376) v = mha_ob[i - 4608];
    else if (i < 6144) v = attn_pb[i - 5376];
    else if (i < 7680) { int j = i - 6144; v = (j < 768) ? 0.f : t2s_kvb[j - 768]; }
    else if (i < 8448) v = t2s_qb[i - 7680];
    else if (i < 9216) v = t2s_pb[i - 8448];
    else if (i < 9984) v = s2t_qb[i - 9216];
    else if (i < 11520) { int j = i - 9984; v = (j < 768) ? 0.f : s2t_kvb[j - 768]; }
    else if (i < 12288) v = s2t_pb[i - 11520];
    else if (i < 15360) v = cfc_b[i - 12288];
    else if (i < 16128) v = cproj_b[i - 15360];
    else if (i < 19200) v = fc1_b[i - 16128];
    else if (i < 19968) v = fc2_b[i - 19200];
    else return;
    dst[i] = v;
}

// ---- block reductions --------------------------------------------------------
__device__ __forceinline__ float block_sum(float v, float* red) {
    #pragma unroll
    for (int o = 32; o > 0; o >>= 1) v += __shfl_down(v, o, 64);
    int w = threadIdx.x >> 6, l = threadIdx.x & 63;
    __syncthreads();
    if (l == 0) red[w] = v;
    __syncthreads();
    return red[0] + red[1] + red[2] + red[3];
}

// ---- LN core -----------------------------------------------------------------
__device__ __forceinline__ void ln_row(const float* xr, const float* g,
                                       const float* bta, u16* yr, float* red) {
    const int t = threadIdx.x;
    float v0 = xr[t], v1 = xr[t + 256], v2 = xr[t + 512];
    float mean = block_sum(v0 + v1 + v2, red) * (1.0f / 768.0f);
    float d0 = v0 - mean, d1 = v1 - mean, d2 = v2 - mean;
    float var = block_sum(d0 * d0 + d1 * d1 + d2 * d2, red) * (1.0f / 768.0f);
    float rs = rsqrtf(var + 1e-5f);
    yr[t]       = f2b(d0 * rs * g[t]       + bta[t]);
    yr[t + 256] = f2b(d1 * rs * g[t + 256] + bta[t + 256]);
    yr[t + 512] = f2b(d2 * rs * g[t + 512] + bta[t + 512]);
}

__global__ __launch_bounds__(256) void ln_dual(
    const float* __restrict__ x, int rows0,
    const float* g0, const float* b0, u16* y0,
    const float* g1, const float* b1, u16* y1) {
    __shared__ float red[4];
    int r = blockIdx.x;
    if (r < rows0) ln_row(x + (size_t)r * 768, g0, b0, y0 + (size_t)r * 768, red);
    else ln_row(x + (size_t)r * 768, g1, b1, y1 + (size_t)(r - rows0) * 768, red);
}

__global__ __launch_bounds__(256) void ln_dual_in(
    const float* __restrict__ xs, const float* __restrict__ xt,
    float* __restrict__ xcopy, int rows0,
    const float* g0, const float* b0, u16* y0,
    const float* g1, const float* b1, u16* y1) {
    __shared__ float red[4];
    int r = blockIdx.x, t = threadIdx.x;
    const float* xr; const float* g; const float* bta; u16* yr;
    if (r < rows0) { xr = xs + (size_t)r * 768; g = g0; bta = b0; yr = y0 + (size_t)r * 768; }
    else { xr = xt + (size_t)(r - rows0) * 768; g = g1; bta = b1; yr = y1 + (size_t)(r - rows0) * 768; }
    float v0 = xr[t], v1 = xr[t + 256], v2 = xr[t + 512];
    float* xc = xcopy + (size_t)r * 768;
    xc[t] = v0; xc[t + 256] = v1; xc[t + 512] = v2;
    float mean = block_sum(v0 + v1 + v2, red) * (1.0f / 768.0f);
    float d0 = v0 - mean, d1 = v1 - mean, d2 = v2 - mean;
    float var = block_sum(d0 * d0 + d1 * d1 + d2 * d2, red) * (1.0f / 768.0f);
    float rs = rsqrtf(var + 1e-5f);
    yr[t]       = f2b(d0 * rs * g[t]       + bta[t]);
    yr[t + 256] = f2b(d1 * rs * g[t + 256] + bta[t + 256]);
    yr[t + 512] = f2b(d2 * rs * g[t + 512] + bta[t + 512]);
}

// ---- V transpose (pairable) ---------------------------------------------------
struct TransP {
    const u16* vp; u16* vt;
    int Nk, Nkp, gx, nb;
    long long vA, vJ;
};
__device__ __forceinline__ void transpose_body(const TransP p, int bid, u16 (*T)[72]) {
    const int x = bid % p.gx, inst = bid / p.gx;
    const int a = inst / 12, h = inst % 12;
    const int t0 = x * 64;
    const int tid = threadIdx.x;
    const int kvl = tid >> 2, dseg = (tid & 3) * 16;
    u16x8 v0 = {}, v1 = {};
    if (t0 + kvl < p.Nk) {
        const u16* src = p.vp + a * p.vA + (long long)(t0 + kvl) * p.vJ + h * 64 + dseg;
        v0 = *(const u16x8*)src;
        v1 = *(const u16x8*)(src + 8);
    }
    *(u16x8*)&T[kvl][dseg]     = v0;
    *(u16x8*)&T[kvl][dseg + 8] = v1;
    __syncthreads();
    const int dl = tid >> 2, kseg = (tid & 3) * 16;
    u16x8 w0, w1;
    #pragma unroll
    for (int j = 0; j < 8; j++) w0[j] = T[kseg + j][dl];
    #pragma unroll
    for (int j = 0; j < 8; j++) w1[j] = T[kseg + 8 + j][dl];
    u16* orow = p.vt + ((size_t)inst * 64 + dl) * p.Nkp + t0 + kseg;
    *(u16x8*)orow = w0;
    *(u16x8*)(orow + 8) = w1;
}
__global__ __launch_bounds__(256) void transpose_pair(TransP p0, TransP p1) {
    __shared__ u16 T[64][72];
    int bid = blockIdx.x;
    if (bid < p0.nb) transpose_body(p0, bid, T);
    else transpose_body(p1, bid - p0.nb, T);
}

// ---- GEMM problem descriptor ---------------------------------------------------
struct GemmP {
    const u16* A; const u16* W; const float* bias;
    u16* Cb; float* Cf;
    int M, N, K, gx, nb;
};

// ---- 128-tile MFMA GEMM body (pairable) ---------------------------------------
template <int MODE, int BM>
__device__ __forceinline__ void gemm_body(const GemmP p, int bid,
                                          u16 (*AsF)[32], u16 (*BsF)[32]) {
    constexpr int MI = BM / 32;
    const int tid = threadIdx.x;
    const int lane = tid & 63;
    const int wid = tid >> 6;
    const int wr = (wid >> 1) * (BM / 2), wc = (wid & 1) * 64;
    const int bx = bid % p.gx, by = bid / p.gx;
    const int m0 = bx * BM, n0 = by * 128;
    const int lr = lane >> 2, lc = (lane & 3) * 8;
    const int fr = lane & 15, fk = (lane >> 4) * 8;
    const int abase = wid * (BM / 4);
    const int bbase = wid * 32;
    f32x4 acc[MI][4] = {};
    for (int k0 = 0; k0 < p.K; k0 += 64) {
        #pragma unroll
        for (int s = 0; s < 2; s++) {
            #pragma unroll
            for (int j = 0; j < BM / 64; j++) {
                int rowa = m0 + abase + j * 16 + lr;
                rowa = rowa < p.M ? rowa : p.M - 1;
                gload16(p.A + (size_t)rowa * p.K + k0 + s * 32 + lc,
                        &AsF[s * 128 + abase + j * 16][0]);
            }
            #pragma unroll
            for (int j = 0; j < 2; j++) {
                gload16(p.W + (size_t)(n0 + bbase + j * 16 + lr) * p.K + k0 + s * 32 + lc,
                        &BsF[s * 128 + bbase + j * 16][0]);
            }
        }
        __syncthreads();
        #pragma unroll
        for (int s = 0; s < 2; s++) {
            bf16x8 a[MI], b[4];
            #pragma unroll
            for (int i = 0; i < MI; i++) a[i] = *(const bf16x8*)&AsF[s * 128 + wr + i * 16 + fr][fk];
            #pragma unroll
            for (int j = 0; j < 4; j++) b[j] = *(const bf16x8*)&BsF[s * 128 + wc + j * 16 + fr][fk];
            #pragma unroll
            for (int i = 0; i < MI; i++)
                #pragma unroll
                for (int j = 0; j < 4; j++)
                    acc[i][j] = __builtin_amdgcn_mfma_f32_16x16x32_bf16(a[i], b[j], acc[i][j], 0, 0, 0);
        }
        __syncthreads();
    }
    const int er = (lane >> 4) * 4;
    #pragma unroll
    for (int i = 0; i < MI; i++) {
        #pragma unroll
        for (int reg = 0; reg < 4; reg++) {
            int r = m0 + wr + i * 16 + er + reg;
            if (r >= p.M) continue;
            #pragma unroll
            for (int j = 0; j < 4; j++) {
                int c = n0 + wc + j * 16 + fr;
                float v = acc[i][j][reg] + p.bias[c];
                size_t idx = (size_t)r * p.N + c;
                if (MODE == 1) {
                    p.Cf[idx] += v;
                } else if (MODE == 4) {
                    float nv = p.Cf[idx] + v;
                    p.Cf[idx] = nv;
                    p.Cb[idx] = f2b(nv);
                } else {
                    if (MODE == 2) v = v / (1.0f + expf(-1.702f * v));
                    if (MODE == 3) v = 0.5f * v * (1.0f + erff(v * 0.70710678118654752f));
                    p.Cb[idx] = f2b(v);
                }
            }
        }
    }
}
template <int M0, int B0, int M1, int B1>
__global__ __launch_bounds__(256) void gemm_pair(GemmP p0, GemmP p1) {
    __shared__ u16 As[2 * 128][32];
    __shared__ u16 Bs[2 * 128][32];
    int bid = blockIdx.x;
    if (bid < p0.nb) gemm_body<M0, B0>(p0, bid, As, Bs);
    else gemm_body<M1, B1>(p1, bid - p0.nb, As, Bs);
}
template <int M0, int B0, int M1, int B1>
__global__ __launch_bounds__(256) void gemm2_trans(GemmP p0, GemmP p1, TransP t0) {
    __shared__ u16 As[2 * 128][32];
    __shared__ u16 Bs[2 * 128][32];
    int bid = blockIdx.x;
    if (bid < p0.nb) gemm_body<M0, B0>(p0, bid, As, Bs);
    else if (bid < p0.nb + p1.nb) gemm_body<M1, B1>(p1, bid - p0.nb, As, Bs);
    else transpose_body(t0, bid - p0.nb - p1.nb, (u16(*)[72])&As[0][0]);
}

// ---- 256x256x64 8-wave GEMM (T2 swizzle + counted-vmcnt pipeline) ------------
// Requires M%256==0 (t-stream only here), N%256==0, K%64==0. Halves of next
// K-tile staged one per phase [B0,B1,A0,A1]; vmcnt(2) before phases 1-2,
// vmcnt(4) before phases 3-4. 2 barriers/K-tile. XCD-bijective swizzle.
template <int MODE>
__global__ __launch_bounds__(512) void gemm256(
    const u16* __restrict__ A, const u16* __restrict__ W,
    const float* __restrict__ bias, u16* __restrict__ Cb,
    float* __restrict__ Cf, int M, int N, int K) {
    __shared__ u16 LA[2][256][64];
    __shared__ u16 LB[2][256][64];
    const int tid = threadIdx.x;
    const int lane = tid & 63, wid = tid >> 6;
    const int wm = wid >> 2, wn = wid & 3;
    int nwg = gridDim.x;
    int q = nwg >> 3, r8 = nwg & 7;
    int xcd = blockIdx.x & 7, orig = blockIdx.x >> 3;
    int bid = (xcd < r8 ? xcd * (q + 1) : r8 * (q + 1) + (xcd - r8) * q) + orig;
    const int gx = M >> 8;
    const int bx = bid % gx, by = bid / gx;
    const int m0 = bx * 256, n0 = by * 256;
    const int srow = tid >> 3;
    const int sgcol = ((tid & 7) * 8) ^ (((tid >> 3) & 7) << 3);
    const u16* Ag = A + (size_t)m0 * K;
    const u16* Bg = W + (size_t)n0 * K;
    const int fr = lane & 15, g = lane >> 4, fk = g * 8;
    const int rsw = (fr & 7) << 3;

    auto stageHalf = [&](u16* half, const u16* gsrc, int rowOff, int kc) {
        #pragma unroll
        for (int c = 0; c < 2; c++) {
            int row = rowOff + c * 64 + srow;
            gload16(gsrc + (size_t)row * K + kc + sgcol,
                    half + c * 4096 + wid * 512);
        }
    };
    auto stage1 = [&](int s, int kc, int which) {
        if (which == 0) stageHalf(&LB[s][0][0],   Bg, 0,   kc);
        else if (which == 1) stageHalf(&LB[s][128][0], Bg, 128, kc);
        else if (which == 2) stageHalf(&LA[s][0][0],   Ag, 0,   kc);
        else stageHalf(&LA[s][128][0], Ag, 128, kc);
    };

    f32x4 acc[8][4] = {};
    const int NT = K >> 6;
    stage1(0, 0, 0); stage1(0, 0, 1); stage1(0, 0, 2); stage1(0, 0, 3);

    for (int kt = 0; kt < NT; kt++) {
        const int cur = kt & 1;
        const int kn = (kt + 1) << 6;
        const bool pf = (kt + 1 < NT);
        asm volatile("s_waitcnt vmcnt(2)" ::: "memory");   // B0,B1,A0 resident
        __builtin_amdgcn_s_barrier();
        bf16x8 bfr[4][2];
        #pragma unroll
        for (int fj = 0; fj < 4; fj++)
            #pragma unroll
            for (int ks = 0; ks < 2; ks++)
                bfr[fj][ks] = *(const bf16x8*)&LB[cur][wn * 64 + fj * 16 + fr][(ks * 32 + fk) ^ rsw];
        #pragma unroll
        for (int ph = 0; ph < 2; ph++) {
            bf16x8 afr[2][2];
            #pragma unroll
            for (int i2 = 0; i2 < 2; i2++)
                #pragma unroll
                for (int ks = 0; ks < 2; ks++)
                    afr[i2][ks] = *(const bf16x8*)&LA[cur][(ph * 2 + i2) * 32 + wm * 16 + fr][(ks * 32 + fk) ^ rsw];
            if (pf) stage1(cur ^ 1, kn, ph);
            __builtin_amdgcn_s_setprio(1);
            #pragma unroll
            for (int i2 = 0; i2 < 2; i2++)
                #pragma unroll
                for (int ks = 0; ks < 2; ks++)
                    #pragma unroll
                    for (int fj = 0; fj < 4; fj++)
                        acc[ph * 2 + i2][fj] = __builtin_amdgcn_mfma_f32_16x16x32_bf16(
                            afr[i2][ks], bfr[fj][ks], acc[ph * 2 + i2][fj], 0, 0, 0);
            __builtin_amdgcn_s_setprio(0);
        }
        if (pf) asm volatile("s_waitcnt vmcnt(4)" ::: "memory");   // A1 resident
        else    asm volatile("s_waitcnt vmcnt(0)" ::: "memory");
        __builtin_amdgcn_s_barrier();
        #pragma unroll
        for (int ph = 2; ph < 4; ph++) {
            bf16x8 afr[2][2];
            #pragma unroll
            for (int i2 = 0; i2 < 2; i2++)
                #pragma unroll
                for (int ks = 0; ks < 2; ks++)
                    afr[i2][ks] = *(const bf16x8*)&LA[cur][(ph * 2 + i2) * 32 + wm * 16 + fr][(ks * 32 + fk) ^ rsw];
            if (pf) stage1(cur ^ 1, kn, ph);
            __builtin_amdgcn_s_setprio(1);
            #pragma unroll
            for (int i2 = 0; i2 < 2; i2++)
                #pragma unroll
                for (int ks = 0; ks < 2; ks++)
                    #pragma unroll
                    for (int fj = 0; fj < 4; fj++)
                        acc[ph * 2 + i2][fj] = __builtin_amdgcn_mfma_f32_16x16x32_bf16(
                            afr[i2][ks], bfr[fj][ks], acc[ph * 2 + i2][fj], 0, 0, 0);
            __builtin_amdgcn_s_setprio(0);
        }
    }
    const int er = g * 4;
    #pragma unroll
    for (int fi = 0; fi < 8; fi++) {
        #pragma unroll
        for (int reg = 0; reg < 4; reg++) {
            int rr = m0 + fi * 32 + wm * 16 + er + reg;
            #pragma unroll
            for (int fj = 0; fj < 4; fj++) {
                int c = n0 + wn * 64 + fj * 16 + fr;
                float v = acc[fi][fj][reg] + bias[c];
                size_t idx = (size_t)rr * N + c;
                if (MODE == 1) {
                    Cf[idx] += v;
                } else if (MODE == 4) {
                    float nv = Cf[idx] + v;
                    Cf[idx] = nv;
                    Cb[idx] = f2b(nv);
                } else {
                    if (MODE == 2) v = v / (1.0f + expf(-1.702f * v));
                    if (MODE == 3) v = 0.5f * v * (1.0f + erff(v * 0.70710678118654752f));
                    Cb[idx] = f2b(v);
                }
            }
        }
    }
}

// ---- MFMA flash attention v5 --------------------------------------------------
struct FlashP {
    const u16* qp; const u16* kp; const u16* vt; u16* op;
    int Nq, Nk, Nkp, gx, nb;
    long long qA, qI, kA, kJ, oA, oI;
};
__device__ __forceinline__ void flash_body(const FlashP p, int bid,
    u16 (*Ks)[64][64], u16 (*Vs)[64][64], u16 (*Ps)[16][64]) {
    const int x = bid % p.gx, inst = bid / p.gx;
    const int a = inst / 12, h = inst % 12;
    const int tid = threadIdx.x, lane = tid & 63, w = tid >> 6;
    const int fr = lane & 15, g = lane >> 4, fk = g * 8;
    const int f3s = (fr & 7) << 3;
    const u16* qb = p.qp + a * p.qA + h * 64;
    const u16* kb = p.kp + a * p.kA + h * 64;
    const u16* vtb = p.vt + (size_t)inst * 64 * p.Nkp;
    const int q0 = x * 64 + w * 16;

    bf16x8 qf[2];
    {
        u16x8 raw0 = {}, raw1 = {};
        int qr = q0 + fr;
        if (qr < p.Nq) {
            const u16* qrp = qb + (long long)qr * p.qI;
            raw0 = *(const u16x8*)(qrp + fk);
            raw1 = *(const u16x8*)(qrp + 32 + fk);
        }
        const float QS = 0.125f * 1.44269504088896340736f;
        u16x8 s0, s1;
        #pragma unroll
        for (int e = 0; e < 8; e++) {
            s0[e] = f2b(b2f(raw0[e]) * QS);
            s1[e] = f2b(b2f(raw1[e]) * QS);
        }
        qf[0] = *(bf16x8*)&s0;
        qf[1] = *(bf16x8*)&s1;
    }
    float mrun = -1e30f, lrun = 0.f;
    f32x4 o[4] = {};

    const int l = lane;
    const int srow = w * 8 + (l >> 3);
    const int sdcol = ((l & 7) * 8) ^ (((l >> 3) & 7) << 3);

    auto STAGE = [&](int s, int t0) {
        #pragma unroll
        for (int c = 0; c < 2; c++) {
            int row = c * 32 + srow;
            int kr = t0 + row; if (kr >= p.Nk) kr = p.Nk - 1;
            gload16(kb + (long long)kr * p.kJ + sdcol, &Ks[s][0][0] + c * 2048 + w * 512);
            gload16(vtb + (size_t)row * p.Nkp + t0 + sdcol, &Vs[s][0][0] + c * 2048 + w * 512);
        }
    };

    const int nt = (p.Nk + 63) >> 6;
    STAGE(0, 0);
    for (int it = 0; it < nt; ++it) {
        const int t0 = it << 6;
        const int cur = it & 1;
        if (it + 1 < nt) {
            STAGE(cur ^ 1, t0 + 64);
            asm volatile("s_waitcnt vmcnt(4)" ::: "memory");
        } else {
            asm volatile("s_waitcnt vmcnt(0)" ::: "memory");
        }
        __builtin_amdgcn_s_barrier();

        f32x4 s[4] = {};
        __builtin_amdgcn_s_setprio(1);
        #pragma unroll
        for (int hh = 0; hh < 4; hh++) {
            bf16x8 k0f = *(const bf16x8*)&Ks[cur][hh * 16 + fr][fk ^ f3s];
            bf16x8 k1f = *(const bf16x8*)&Ks[cur][hh * 16 + fr][(32 + fk) ^ f3s];
            s[hh] = __builtin_amdgcn_mfma_f32_16x16x32_bf16(k0f, qf[0], s[hh], 0, 0, 0);
            s[hh] = __builtin_amdgcn_mfma_f32_16x16x32_bf16(k1f, qf[1], s[hh], 0, 0, 0);
        }
        __builtin_amdgcn_s_setprio(0);

        if (t0 + 64 > p.Nk) {
            #pragma unroll
            for (int hh = 0; hh < 4; hh++)
                #pragma unroll
                for (int r = 0; r < 4; r++)
                    if (t0 + hh * 16 + 4 * g + r >= p.Nk) s[hh][r] = -1e30f;
        }
        float a0 = fmaxf(fmaxf(s[0][0], s[0][1]), s[0][2]);
        float a1 = fmaxf(fmaxf(s[0][3], s[1][0]), s[1][1]);
        float a2 = fmaxf(fmaxf(s[1][2], s[1][3]), s[2][0]);
        float a3 = fmaxf(fmaxf(s[2][1], s[2][2]), s[2][3]);
        float a4 = fmaxf(fmaxf(s[3][0], s[3][1]), s[3][2]);
        float b0 = fmaxf(fmaxf(a0, a1), a2);
        float b1 = fmaxf(fmaxf(a3, a4), s[3][3]);
        float lmax = fmaxf(b0, b1);
        lmax = fmaxf(lmax, __shfl_xor(lmax, 16, 64));
        lmax = fmaxf(lmax, __shfl_xor(lmax, 32, 64));
        if (!__all(lmax <= mrun + 8.0f)) {
            float mn = fmaxf(mrun, lmax);
            float sf = exp2f(mrun - mn);
            mrun = mn;
            lrun *= sf;
            float sfo[4];
            #pragma unroll
            for (int r = 0; r < 4; r++) sfo[r] = __shfl(sf, g * 4 + r, 64);
            #pragma unroll
            for (int dt = 0; dt < 4; dt++)
                #pragma unroll
                for (int r = 0; r < 4; r++) o[dt][r] *= sfo[r];
        }
        float pp[4][4];
        float ps = 0.f;
        #pragma unroll
        for (int hh = 0; hh < 4; hh++)
            #pragma unroll
            for (int r = 0; r < 4; r++) {
                pp[hh][r] = exp2f(s[hh][r] - mrun);
                ps += pp[hh][r];
            }
        ps += __shfl_xor(ps, 16, 64);
        ps += __shfl_xor(ps, 32, 64);
        lrun += ps;
        #pragma unroll
        for (int hh = 0; hh < 4; hh++) {
            u16x4 pk;
            #pragma unroll
            for (int r = 0; r < 4; r++) pk[r] = f2b_trunc(pp[hh][r]);
            *(u16x4*)&Ps[w][fr][(hh * 16 + g * 4) ^ f3s] = pk;
        }
        bf16x8 pa0 = *(const bf16x8*)&Ps[w][fr][fk ^ f3s];
        bf16x8 pa1 = *(const bf16x8*)&Ps[w][fr][(32 + fk) ^ f3s];
        __builtin_amdgcn_s_setprio(1);
        #pragma unroll
        for (int dt = 0; dt < 4; dt++) {
            bf16x8 vf0 = *(const bf16x8*)&Vs[cur][dt * 16 + fr][fk ^ f3s];
            bf16x8 vf1 = *(const bf16x8*)&Vs[cur][dt * 16 + fr][(32 + fk) ^ f3s];
            o[dt] = __builtin_amdgcn_mfma_f32_16x16x32_bf16(pa0, vf0, o[dt], 0, 0, 0);
            o[dt] = __builtin_amdgcn_mfma_f32_16x16x32_bf16(pa1, vf1, o[dt], 0, 0, 0);
        }
        __builtin_amdgcn_s_setprio(0);
        __builtin_amdgcn_s_barrier();
    }
    float rcp = 1.0f / lrun;
    #pragma unroll
    for (int r = 0; r < 4; r++) {
        float rr = __shfl(rcp, g * 4 + r, 64);
        int qq = q0 + g * 4 + r;
        if (qq >= p.Nq) continue;
        u16* orow = p.op + a * p.oA + (long long)qq * p.oI + h * 64;
        #pragma unroll
        for (int dt = 0; dt < 4; dt++)
            orow[dt * 16 + fr] = f2b(o[dt][r] * rr);
    }
}
__global__ __launch_bounds__(256) void flash_pair(FlashP p0, FlashP p1) {
    __shared__ u16 Ks[2][64][64];
    __shared__ u16 Vs[2][64][64];
    __shared__ u16 Ps[4][16][64];
    int bid = blockIdx.x;
    if (bid < p0.nb) flash_body(p0, bid, Ks, Vs, Ps);
    else flash_body(p1, bid - p0.nb, Ks, Vs, Ps);
}

// ---------------------------------------------------------------------------
extern "C" void kernel_launch(void* const* d_in, const int* in_sizes, int n_in,
                              void* d_out, int out_size, void* d_ws, size_t ws_size,
                              hipStream_t stream) {
    const int B = 8, sN = 196, tN = 1568;
    const int Ms = B * sN;            // 1568
    const int Mt = B * tN;            // 12544
    const int n_sf = Ms * 768;
    const int n_tf = Mt * 768;
    (void)n_in; (void)out_size; (void)ws_size;

    const bool dict_order = (in_sizes[0] == n_sf);
    auto IN = [&](int di, int ai) -> const float* {
        return (const float*)d_in[dict_order ? di : ai];
    };
    const float* in_sx      = IN(0, 35);
    const float* in_tx      = IN(1, 42);
    const float* ln1s_g     = IN(2, 14);
    const float* ln1s_b     = IN(3, 13);
    const float* mha_w      = IN(4, 28);
    const float* mha_b      = IN(5, 25);
    const float* mha_ow     = IN(6, 27);
    const float* mha_ob     = IN(7, 26);
    const float* ln1t_g     = IN(8, 16);
    const float* ln1t_b     = IN(9, 15);
    const float* attn_qkv_w = IN(10, 3);
    const float* attn_q_b   = IN(11, 2);
    const float* attn_v_b   = IN(12, 4);
    const float* attn_pw    = IN(13, 1);
    const float* attn_pb    = IN(14, 0);
    const float* lnt2s_g    = IN(15, 24);
    const float* lnt2s_b    = IN(16, 23);
    const float* t2s_qw     = IN(17, 41);
    const float* t2s_qb     = IN(18, 40);
    const float* t2s_kvw    = IN(19, 37);
    const float* t2s_kvb    = IN(20, 36);
    const float* t2s_pw     = IN(21, 39);
    const float* t2s_pb     = IN(22, 38);
    const float* lns2t_g    = IN(23, 22);
    const float* lns2t_b    = IN(24, 21);
    const float* s2t_qw     = IN(25, 34);
    const float* s2t_qb     = IN(26, 33);
    const float* s2t_kvw    = IN(27, 30);
    const float* s2t_kvb    = IN(28, 29);
    const float* s2t_pw     = IN(29, 32);
    const float* s2t_pb     = IN(30, 31);
    const float* ln2s_g     = IN(31, 18);
    const float* ln2s_b     = IN(32, 17);
    const float* cfc_w      = IN(33, 6);
    const float* cfc_b      = IN(34, 5);
    const float* cproj_w    = IN(35, 8);
    const float* cproj_b    = IN(36, 7);
    const float* ln2t_g     = IN(37, 20);
    const float* ln2t_b     = IN(38, 19);
    const float* fc1_w      = IN(39, 10);
    const float* fc1_b      = IN(40, 9);
    const float* fc2_w      = IN(41, 12);
    const float* fc2_b      = IN(42, 11);

    float* s_f = (float*)d_out;
    float* t_f = (float*)d_out + n_sf;

    // ---- workspace ----------------------------------------------------------
    char* ws = (char*)d_ws;
    size_t off = 0;
    auto take = [&](size_t bytes) { size_t o = off; off += (bytes + 255) & ~(size_t)255; return o; };
    float* biasP = (float*)(ws + take(19968 * 4));
    u16*   yb    = (u16*)(ws + take((size_t)(Ms + Mt) * 768 * 2));
    u16*   bufA  = (u16*)(ws + take((size_t)Mt * 3072 * 2));
    u16*   bufS  = (u16*)(ws + take((size_t)Mt * 768 * 2));
    u16*   bufB  = (u16*)(ws + take((size_t)Mt * 768 * 2));
    u16*   sxb   = (u16*)(ws + take((size_t)Ms * 768 * 2));
    u16*   vtb_t = (u16*)(ws + take((size_t)96 * 64 * 1600 * 2));
    u16*   yb_s  = yb;
    u16*   yb_t  = yb + (size_t)Ms * 768;
    u16*   vtb_s = yb;   // alias: live only while yb fully dead (steps 6-7)
    auto wtake = [&](size_t nelem) { return (u16*)(ws + take(nelem * 2)); };
    u16 *W_mha   = wtake(2304 * 768), *W_mhao  = wtake(768 * 768);
    u16 *W_qkv   = wtake(2304 * 768), *W_attnp = wtake(768 * 768);
    u16 *W_t2sq  = wtake(768 * 768),  *W_t2skv = wtake(1536 * 768), *W_t2sp = wtake(768 * 768);
    u16 *W_s2tq  = wtake(768 * 768),  *W_s2tkv = wtake(1536 * 768), *W_s2tp = wtake(768 * 768);
    u16 *W_cfc   = wtake(3072 * 768), *W_cproj = wtake(768 * 3072);
    u16 *W_fc1   = wtake(3072 * 768), *W_fc2   = wtake(768 * 3072);

    const int B_MHA = 0, B_QKV = 2304, B_MHAO = 4608, B_ATTNP = 5376;
    const int B_T2SKV = 6144, B_T2SQ = 7680, B_T2SP = 8448, B_S2TQ = 9216;
    const int B_S2TKV = 9984, B_S2TP = 11520, B_CFC = 12288, B_CPROJ = 15360;
    const int B_FC1 = 16128, B_FC2 = 19200;

    auto cdiv = [](int a, int b) { return (a + b - 1) / b; };

    // 1. weights -> bf16
    {
        CvtAll c;
        const float* ss[14] = { mha_w, mha_ow, attn_qkv_w, attn_pw, t2s_qw, t2s_kvw, t2s_pw,
                                s2t_qw, s2t_kvw, s2t_pw, cfc_w, cproj_w, fc1_w, fc2_w };
        u16* dd[14] = { W_mha, W_mhao, W_qkv, W_attnp, W_t2sq, W_t2skv, W_t2sp,
                        W_s2tq, W_s2tkv, W_s2tp, W_cfc, W_cproj, W_fc1, W_fc2 };
        int nn[14] = { 2304*768, 768*768, 2304*768, 768*768, 768*768, 1536*768, 768*768,
                       768*768, 1536*768, 768*768, 3072*768, 768*3072, 3072*768, 768*3072 };
        int cum = 0;
        for (int k = 0; k < 14; k++) { c.s[k] = ss[k]; c.d[k] = dd[k]; c.cum[k] = cum; cum += nn[k]; }
        c.cum[14] = cum;
        cvt_all<<<cdiv(cum, 256), 256, 0, stream>>>(c);
    }
    // 2. bias pool
    build_bias_pool<<<78, 256, 0, stream>>>(biasP,
        mha_b, attn_q_b, attn_v_b, mha_ob, attn_pb, t2s_kvb, t2s_qb, t2s_pb,
        s2t_qb, s2t_kvb, s2t_pb, cfc_b, cproj_b, fc1_b, fc2_b);

    auto GP = [&](const u16* A, const u16* W, const float* bias, u16* Cb, float* Cf,
                  int M, int N, int K, int BM) {
        GemmP p; p.A = A; p.W = W; p.bias = bias; p.Cb = Cb; p.Cf = Cf;
        p.M = M; p.N = N; p.K = K; p.gx = (M + BM - 1) / BM; p.nb = p.gx * (N / 128);
        return p;
    };
    auto ZERO = [&](GemmP p) { GemmP z = p; z.nb = 0; return z; };
    auto FPm = [&](const u16* qp, const u16* kp, const u16* vt, u16* op,
                   int Nq, int Nk, int Nkp, int insts,
                   long long qA, long long qI, long long kA, long long kJ,
                   long long oA, long long oI) {
        FlashP p; p.qp = qp; p.kp = kp; p.vt = vt; p.op = op;
        p.Nq = Nq; p.Nk = Nk; p.Nkp = Nkp; p.gx = (Nq + 63) / 64;
        p.nb = p.gx * insts;
        p.qA = qA; p.qI = qI; p.kA = kA; p.kJ = kJ; p.oA = oA; p.oI = oI;
        return p;
    };
    auto TP = [&](const u16* vp, u16* vt, int Nk, int Nkp, long long vA, long long vJ, int insts) {
        TransP p; p.vp = vp; p.vt = vt; p.Nk = Nk; p.Nkp = Nkp;
        p.gx = (Nk + 63) / 64; p.nb = p.gx * insts; p.vA = vA; p.vJ = vJ;
        return p;
    };

    // 3. stream copy + LN1 pair
    ln_dual_in<<<Ms + Mt, 256, 0, stream>>>(in_sx, in_tx, (float*)d_out, Ms,
        ln1s_g, ln1s_b, yb_s, ln1t_g, ln1t_b, yb_t);

    // 4. qkv_t (256-tile, 441 blocks)
    gemm256<0><<<49 * (2304 / 256), 512, 0, stream>>>(yb_t, W_qkv, biasP + B_QKV, bufA, (float*)0, Mt, 2304, 768);
    // 5. qkv_s (128-tile BM=64, dense)
    {
        GemmP p0 = GP(yb_s, W_mha, biasP + B_MHA, bufS, 0, Ms, 2304, 768, 64);
        gemm_pair<0, 64, 0, 64><<<p0.nb, 256, 0, stream>>>(p0, ZERO(p0));
    }
    // 6. transpose pair
    {
        TransP p0 = TP(bufS + 1536, vtb_s, 8, 64, 2304LL, (long long)sN * 2304, sN * 12);
        TransP p1 = TP(bufA + 1536, vtb_t, tN, 1600, (long long)tN * 2304, 2304LL, B * 12);
        transpose_pair<<<p0.nb + p1.nb, 256, 0, stream>>>(p0, p1);
    }
    // 7. flash pair (stage1 -> sxb, stage2 -> bufB)
    {
        FlashP p0 = FPm(bufS, bufS + 768, vtb_s, sxb, 8, 8, 64, sN * 12,
                        2304LL, (long long)sN * 2304, 2304LL, (long long)sN * 2304,
                        768LL, (long long)sN * 768);
        FlashP p1 = FPm(bufA, bufA + 768, vtb_t, bufB, tN, tN, 1600, B * 12,
                        (long long)tN * 2304, 2304LL, (long long)tN * 2304, 2304LL,
                        (long long)tN * 768, 768LL);
        flash_pair<<<p0.nb + p1.nb, 256, 0, stream>>>(p0, p1);
    }
    // 8. proj pair (mha MODE1 || attn MODE4 -> t_f + yb_t)
    {
        GemmP p0 = GP(sxb, W_mhao, biasP + B_MHAO, 0, s_f, Ms, 768, 768, 64);
        GemmP p1 = GP(bufB, W_attnp, biasP + B_ATTNP, yb_t, t_f, Mt, 768, 768, 128);
        gemm_pair<1, 64, 4, 128><<<p0.nb + p1.nb, 256, 0, stream>>>(p0, p1);
    }
    // 9. LN pair: lnt2s -> yb_s || lns2t -> bufB
    ln_dual<<<Ms + Mt, 256, 0, stream>>>((const float*)d_out, Ms,
        lnt2s_g, lnt2s_b, yb_s, lns2t_g, lns2t_b, bufB);
    // 10. t2s_kv (256-tile, 294 blocks)
    gemm256<0><<<49 * (1536 / 256), 512, 0, stream>>>(yb_t, W_t2skv, biasP + B_T2SKV, bufA, (float*)0, Mt, 1536, 768);
    // 11. s2t_q || t2s_q || transpose(t2s V)
    {
        GemmP p0 = GP(bufB, W_s2tq, biasP + B_S2TQ, bufS, 0, Mt, 768, 768, 128);
        GemmP p1 = GP(yb_s, W_t2sq, biasP + B_T2SQ, sxb, 0, Ms, 768, 768, 64);
        TransP t0 = TP(bufA + 768, vtb_t, tN, 1600, (long long)tN * 1536, 1536LL, B * 12);
        gemm2_trans<0, 128, 0, 64><<<p0.nb + p1.nb + t0.nb, 256, 0, stream>>>(p0, p1, t0);
    }
    // 12. flash stage3 -> yb_s
    {
        FlashP p0 = FPm(sxb, bufA, vtb_t, yb_s, sN, tN, 1600, B * 12,
                        (long long)sN * 768, 768LL, (long long)tN * 1536, 1536LL,
                        (long long)sN * 768, 768LL);
        FlashP pz = p0; pz.nb = 0;
        flash_pair<<<p0.nb, 256, 0, stream>>>(p0, pz);
    }
    // 13. t2s proj (MODE4 -> s_f + sxb mirror)
    {
        GemmP p0 = GP(yb_s, W_t2sp, biasP + B_T2SP, sxb, s_f, Ms, 768, 768, 64);
        gemm_pair<4, 64, 4, 64><<<p0.nb, 256, 0, stream>>>(p0, ZERO(p0));
    }
    // 14. LN ln2s -> yb_s
    ln_dual<<<Ms, 256, 0, stream>>>((const float*)d_out, Ms,
        ln2s_g, ln2s_b, yb_s, ln2s_g, ln2s_b, yb_s);
    // 15. s2t_kv || cfc (QuickGELU -> yb_t)
    {
        GemmP p0 = GP(sxb, W_s2tkv, biasP + B_S2TKV, bufB, 0, Ms, 1536, 768, 64);
        GemmP p1 = GP(yb_s, W_cfc, biasP + B_CFC, yb_t, 0, Ms, 3072, 768, 64);
        gemm_pair<0, 64, 2, 64><<<p0.nb + p1.nb, 256, 0, stream>>>(p0, p1);
    }
    // 16. cproj (MODE1 -> s_f) || transpose(s2t V -> bufA)
    {
        GemmP p0 = GP(yb_t, W_cproj, biasP + B_CPROJ, 0, s_f, Ms, 768, 3072, 64);
        TransP t0 = TP(bufB + 768, bufA, sN, 256, (long long)sN * 1536, 1536LL, B * 12);
        gemm2_trans<1, 64, 1, 64><<<p0.nb + t0.nb, 256, 0, stream>>>(p0, ZERO(p0), t0);
    }
    // 17. flash stage4 -> yb
    {
        FlashP p0 = FPm(bufS, bufB, bufA, yb, tN, sN, 256, B * 12,
                        (long long)tN * 768, 768LL, (long long)sN * 1536, 1536LL,
                        (long long)tN * 768, 768LL);
        FlashP pz = p0; pz.nb = 0;
        flash_pair<<<p0.nb, 256, 0, stream>>>(p0, pz);
    }
    // 18. s2t proj (256-tile, MODE1 -> t_f)
    gemm256<1><<<49 * (768 / 256), 512, 0, stream>>>(yb, W_s2tp, biasP + B_S2TP, (u16*)0, t_f, Mt, 768, 768);
    // 19. LN ln2t -> yb_t
    ln_dual<<<Mt, 256, 0, stream>>>(t_f, 0,
        ln2t_g, ln2t_b, yb_t, ln2t_g, ln2t_b, yb_t);
    // 20. fc1 (256-tile, exact GELU -> bufA, 588 blocks)
    gemm256<3><<<49 * (3072 / 256), 512, 0, stream>>>(yb_t, W_fc1, biasP + B_FC1, bufA, (float*)0, Mt, 3072, 768);
    // 21. fc2 (256-tile, MODE1 -> t_f, K=3072 deep pipeline)
    gemm256<1><<<49 * (768 / 256), 512, 0, stream>>>(bufA, W_fc2, biasP + B_FC2, (u16*)0, t_f, Mt, 768, 3072);
}

// Round 21
// 899.234 us; speedup vs baseline: 1.0818x; 1.0035x over previous
//
#include <hip/hip_runtime.h>
#include <stdint.h>

// ---------------------------------------------------------------------------
// Block_6554120094246: dual-stream transformer block (CLIP + video streams).
// f32 in/out. Residual streams in d_out. bf16 intermediates.
// Schedule = measured-best R18 config (900us). MFMA flash attention v5 with
// v_perm P-pack (bit-identical truncation, fewer VALU ops on the bound pipe).
// ---------------------------------------------------------------------------

typedef uint16_t u16;
typedef uint16_t u16x8 __attribute__((ext_vector_type(8)));
typedef uint16_t u16x4 __attribute__((ext_vector_type(4)));
typedef uint32_t u32x2 __attribute__((ext_vector_type(2)));
typedef short bf16x8 __attribute__((ext_vector_type(8)));
typedef float f32x4 __attribute__((ext_vector_type(4)));

__device__ __forceinline__ float b2f(u16 u) {
    union { float f; uint32_t i; } x;
    x.i = ((uint32_t)u) << 16;
    return x.f;
}
__device__ __forceinline__ u16 f2b(float f) {
    union { float f; uint32_t i; } x;
    x.f = f;
    uint32_t i = x.i;
    uint32_t r = (i + 0x7FFFu + ((i >> 16) & 1u)) >> 16;  // RNE
    return (u16)r;
}
__device__ __forceinline__ uint32_t fbits(float f) {
    union { float f; uint32_t i; } x; x.f = f; return x.i;
}

// async global->LDS, 16B per lane; LDS dest wave-uniform base (+lane*16B).
__device__ __forceinline__ void gload16(const u16* g, u16* l) {
    __builtin_amdgcn_global_load_lds(
        (const __attribute__((address_space(1))) uint32_t*)g,
        (__attribute__((address_space(3))) uint32_t*)l, 16, 0, 0);
}

// ---- mega weight convert (one launch, 14 segments) --------------------------
struct CvtAll {
    const float* s[14];
    u16* d[14];
    int cum[15];
};
__global__ __launch_bounds__(256) void cvt_all(CvtAll c) {
    int i = blockIdx.x * 256 + threadIdx.x;
    if (i >= c.cum[14]) return;
    int seg = 0;
    #pragma unroll
    for (int k = 1; k < 14; k++) seg += (i >= c.cum[k]);
    int j = i - c.cum[seg];
    c.d[seg][j] = f2b(c.s[seg][j]);
}

// ---- bias pool ---------------------------------------------------------------
__global__ __launch_bounds__(256) void build_bias_pool(float* __restrict__ dst,
    const float* mha_b, const float* attn_q_b, const float* attn_v_b,
    const float* mha_ob, const float* attn_pb, const float* t2s_kvb,
    const float* t2s_qb, const float* t2s_pb, const float* s2t_qb,
    const float* s2t_kvb, const float* s2t_pb, const float* cfc_b,
    const float* cproj_b, const float* fc1_b, const float* fc2_b) {
    int i = blockIdx.x * 256 + threadIdx.x;
    float v = 0.f;
    if (i < 2304) v = mha_b[i];
    else if (i < 4608) { int j = i - 2304; v = (j < 768) ? attn_q_b[j] : (j < 1536 ? 0.f : attn_v_b[j - 1536]); }
    else if (i < 5376) v = mha_ob[i - 4608];
    else if (i < 6144) v = attn_pb[i - 5376];
    else if (i < 7680) { int j = i - 6144; v = (j < 768) ? 0.f : t2s_kvb[j - 768]; }
    else if (i < 8448) v = t2s_qb[i - 7680];
    else if (i < 9216) v = t2s_pb[i - 8448];
    else if (i < 9984) v = s2t_qb[i - 9216];
    else if (i < 11520) { int j = i - 9984; v = (j < 768) ? 0.f : s2t_kvb[j - 768]; }
    else if (i < 12288) v = s2t_pb[i - 11520];
    else if (i < 15360) v = cfc_b[i - 12288];
    else if (i < 16128) v = cproj_b[i - 15360];
    else if (i < 19200) v = fc1_b[i - 16128];
    else if (i < 19968) v = fc2_b[i - 19200];
    else return;
    dst[i] = v;
}

// ---- block reductions --------------------------------------------------------
__device__ __forceinline__ float block_sum(float v, float* red) {
    #pragma unroll
    for (int o = 32; o > 0; o >>= 1) v += __shfl_down(v, o, 64);
    int w = threadIdx.x >> 6, l = threadIdx.x & 63;
    __syncthreads();
    if (l == 0) red[w] = v;
    __syncthreads();
    return red[0] + red[1] + red[2] + red[3];
}

// ---- LN core -----------------------------------------------------------------
__device__ __forceinline__ void ln_row(const float* xr, const float* g,
                                       const float* bta, u16* yr, float* red) {
    const int t = threadIdx.x;
    float v0 = xr[t], v1 = xr[t + 256], v2 = xr[t + 512];
    float mean = block_sum(v0 + v1 + v2, red) * (1.0f / 768.0f);
    float d0 = v0 - mean, d1 = v1 - mean, d2 = v2 - mean;
    float var = block_sum(d0 * d0 + d1 * d1 + d2 * d2, red) * (1.0f / 768.0f);
    float rs = rsqrtf(var + 1e-5f);
    yr[t]       = f2b(d0 * rs * g[t]       + bta[t]);
    yr[t + 256] = f2b(d1 * rs * g[t + 256] + bta[t + 256]);
    yr[t + 512] = f2b(d2 * rs * g[t + 512] + bta[t + 512]);
}

__global__ __launch_bounds__(256) void ln_dual(
    const float* __restrict__ x, int rows0,
    const float* g0, const float* b0, u16* y0,
    const float* g1, const float* b1, u16* y1) {
    __shared__ float red[4];
    int r = blockIdx.x;
    if (r < rows0) ln_row(x + (size_t)r * 768, g0, b0, y0 + (size_t)r * 768, red);
    else ln_row(x + (size_t)r * 768, g1, b1, y1 + (size_t)(r - rows0) * 768, red);
}

__global__ __launch_bounds__(256) void ln_dual_in(
    const float* __restrict__ xs, const float* __restrict__ xt,
    float* __restrict__ xcopy, int rows0,
    const float* g0, const float* b0, u16* y0,
    const float* g1, const float* b1, u16* y1) {
    __shared__ float red[4];
    int r = blockIdx.x, t = threadIdx.x;
    const float* xr; const float* g; const float* bta; u16* yr;
    if (r < rows0) { xr = xs + (size_t)r * 768; g = g0; bta = b0; yr = y0 + (size_t)r * 768; }
    else { xr = xt + (size_t)(r - rows0) * 768; g = g1; bta = b1; yr = y1 + (size_t)(r - rows0) * 768; }
    float v0 = xr[t], v1 = xr[t + 256], v2 = xr[t + 512];
    float* xc = xcopy + (size_t)r * 768;
    xc[t] = v0; xc[t + 256] = v1; xc[t + 512] = v2;
    float mean = block_sum(v0 + v1 + v2, red) * (1.0f / 768.0f);
    float d0 = v0 - mean, d1 = v1 - mean, d2 = v2 - mean;
    float var = block_sum(d0 * d0 + d1 * d1 + d2 * d2, red) * (1.0f / 768.0f);
    float rs = rsqrtf(var + 1e-5f);
    yr[t]       = f2b(d0 * rs * g[t]       + bta[t]);
    yr[t + 256] = f2b(d1 * rs * g[t + 256] + bta[t + 256]);
    yr[t + 512] = f2b(d2 * rs * g[t + 512] + bta[t + 512]);
}

// ---- V transpose (pairable) ---------------------------------------------------
struct TransP {
    const u16* vp; u16* vt;
    int Nk, Nkp, gx, nb;
    long long vA, vJ;
};
__device__ __forceinline__ void transpose_body(const TransP p, int bid, u16 (*T)[72]) {
    const int x = bid % p.gx, inst = bid / p.gx;
    const int a = inst / 12, h = inst % 12;
    const int t0 = x * 64;
    const int tid = threadIdx.x;
    const int kvl = tid >> 2, dseg = (tid & 3) * 16;
    u16x8 v0 = {}, v1 = {};
    if (t0 + kvl < p.Nk) {
        const u16* src = p.vp + a * p.vA + (long long)(t0 + kvl) * p.vJ + h * 64 + dseg;
        v0 = *(const u16x8*)src;
        v1 = *(const u16x8*)(src + 8);
    }
    *(u16x8*)&T[kvl][dseg]     = v0;
    *(u16x8*)&T[kvl][dseg + 8] = v1;
    __syncthreads();
    const int dl = tid >> 2, kseg = (tid & 3) * 16;
    u16x8 w0, w1;
    #pragma unroll
    for (int j = 0; j < 8; j++) w0[j] = T[kseg + j][dl];
    #pragma unroll
    for (int j = 0; j < 8; j++) w1[j] = T[kseg + 8 + j][dl];
    u16* orow = p.vt + ((size_t)inst * 64 + dl) * p.Nkp + t0 + kseg;
    *(u16x8*)orow = w0;
    *(u16x8*)(orow + 8) = w1;
}
__global__ __launch_bounds__(256) void transpose_pair(TransP p0, TransP p1) {
    __shared__ u16 T[64][72];
    int bid = blockIdx.x;
    if (bid < p0.nb) transpose_body(p0, bid, T);
    else transpose_body(p1, bid - p0.nb, T);
}

// ---- GEMM problem descriptor ---------------------------------------------------
struct GemmP {
    const u16* A; const u16* W; const float* bias;
    u16* Cb; float* Cf;
    int M, N, K, gx, nb;
};

// ---- 128-tile MFMA GEMM body (pairable) ---------------------------------------
template <int MODE, int BM>
__device__ __forceinline__ void gemm_body(const GemmP p, int bid,
                                          u16 (*AsF)[32], u16 (*BsF)[32]) {
    constexpr int MI = BM / 32;
    const int tid = threadIdx.x;
    const int lane = tid & 63;
    const int wid = tid >> 6;
    const int wr = (wid >> 1) * (BM / 2), wc = (wid & 1) * 64;
    const int bx = bid % p.gx, by = bid / p.gx;
    const int m0 = bx * BM, n0 = by * 128;
    const int lr = lane >> 2, lc = (lane & 3) * 8;
    const int fr = lane & 15, fk = (lane >> 4) * 8;
    const int abase = wid * (BM / 4);
    const int bbase = wid * 32;
    f32x4 acc[MI][4] = {};
    for (int k0 = 0; k0 < p.K; k0 += 64) {
        #pragma unroll
        for (int s = 0; s < 2; s++) {
            #pragma unroll
            for (int j = 0; j < BM / 64; j++) {
                int rowa = m0 + abase + j * 16 + lr;
                rowa = rowa < p.M ? rowa : p.M - 1;
                gload16(p.A + (size_t)rowa * p.K + k0 + s * 32 + lc,
                        &AsF[s * 128 + abase + j * 16][0]);
            }
            #pragma unroll
            for (int j = 0; j < 2; j++) {
                gload16(p.W + (size_t)(n0 + bbase + j * 16 + lr) * p.K + k0 + s * 32 + lc,
                        &BsF[s * 128 + bbase + j * 16][0]);
            }
        }
        __syncthreads();
        #pragma unroll
        for (int s = 0; s < 2; s++) {
            bf16x8 a[MI], b[4];
            #pragma unroll
            for (int i = 0; i < MI; i++) a[i] = *(const bf16x8*)&AsF[s * 128 + wr + i * 16 + fr][fk];
            #pragma unroll
            for (int j = 0; j < 4; j++) b[j] = *(const bf16x8*)&BsF[s * 128 + wc + j * 16 + fr][fk];
            #pragma unroll
            for (int i = 0; i < MI; i++)
                #pragma unroll
                for (int j = 0; j < 4; j++)
                    acc[i][j] = __builtin_amdgcn_mfma_f32_16x16x32_bf16(a[i], b[j], acc[i][j], 0, 0, 0);
        }
        __syncthreads();
    }
    const int er = (lane >> 4) * 4;
    #pragma unroll
    for (int i = 0; i < MI; i++) {
        #pragma unroll
        for (int reg = 0; reg < 4; reg++) {
            int r = m0 + wr + i * 16 + er + reg;
            if (r >= p.M) continue;
            #pragma unroll
            for (int j = 0; j < 4; j++) {
                int c = n0 + wc + j * 16 + fr;
                float v = acc[i][j][reg] + p.bias[c];
                size_t idx = (size_t)r * p.N + c;
                if (MODE == 1) {
                    p.Cf[idx] += v;
                } else if (MODE == 4) {
                    float nv = p.Cf[idx] + v;
                    p.Cf[idx] = nv;
                    p.Cb[idx] = f2b(nv);
                } else {
                    if (MODE == 2) v = v / (1.0f + expf(-1.702f * v));
                    if (MODE == 3) v = 0.5f * v * (1.0f + erff(v * 0.70710678118654752f));
                    p.Cb[idx] = f2b(v);
                }
            }
        }
    }
}
template <int M0, int B0, int M1, int B1>
__global__ __launch_bounds__(256) void gemm_pair(GemmP p0, GemmP p1) {
    __shared__ u16 As[2 * 128][32];
    __shared__ u16 Bs[2 * 128][32];
    int bid = blockIdx.x;
    if (bid < p0.nb) gemm_body<M0, B0>(p0, bid, As, Bs);
    else gemm_body<M1, B1>(p1, bid - p0.nb, As, Bs);
}
template <int M0, int B0, int M1, int B1>
__global__ __launch_bounds__(256) void gemm2_trans(GemmP p0, GemmP p1, TransP t0) {
    __shared__ u16 As[2 * 128][32];
    __shared__ u16 Bs[2 * 128][32];
    int bid = blockIdx.x;
    if (bid < p0.nb) gemm_body<M0, B0>(p0, bid, As, Bs);
    else if (bid < p0.nb + p1.nb) gemm_body<M1, B1>(p1, bid - p0.nb, As, Bs);
    else transpose_body(t0, bid - p0.nb - p1.nb, (u16(*)[72])&As[0][0]);
}

// ---- 256x256x64 8-wave GEMM (T2 swizzle + counted-vmcnt pipeline) ------------
template <int MODE>
__global__ __launch_bounds__(512) void gemm256(
    const u16* __restrict__ A, const u16* __restrict__ W,
    const float* __restrict__ bias, u16* __restrict__ Cb,
    float* __restrict__ Cf, int M, int N, int K) {
    __shared__ u16 LA[2][256][64];
    __shared__ u16 LB[2][256][64];
    const int tid = threadIdx.x;
    const int lane = tid & 63, wid = tid >> 6;
    const int wm = wid >> 2, wn = wid & 3;
    int nwg = gridDim.x;
    int q = nwg >> 3, r8 = nwg & 7;
    int xcd = blockIdx.x & 7, orig = blockIdx.x >> 3;
    int bid = (xcd < r8 ? xcd * (q + 1) : r8 * (q + 1) + (xcd - r8) * q) + orig;
    const int gx = M >> 8;
    const int bx = bid % gx, by = bid / gx;
    const int m0 = bx * 256, n0 = by * 256;
    const int srow = tid >> 3;
    const int sgcol = ((tid & 7) * 8) ^ (((tid >> 3) & 7) << 3);
    const u16* Ag = A + (size_t)m0 * K;
    const u16* Bg = W + (size_t)n0 * K;
    const int fr = lane & 15, g = lane >> 4, fk = g * 8;
    const int rsw = (fr & 7) << 3;

    auto stageHalf = [&](u16* half, const u16* gsrc, int rowOff, int kc) {
        #pragma unroll
        for (int c = 0; c < 2; c++) {
            int row = rowOff + c * 64 + srow;
            gload16(gsrc + (size_t)row * K + kc + sgcol,
                    half + c * 4096 + wid * 512);
        }
    };
    auto stage1 = [&](int s, int kc, int which) {
        if (which == 0) stageHalf(&LB[s][0][0],   Bg, 0,   kc);
        else if (which == 1) stageHalf(&LB[s][128][0], Bg, 128, kc);
        else if (which == 2) stageHalf(&LA[s][0][0],   Ag, 0,   kc);
        else stageHalf(&LA[s][128][0], Ag, 128, kc);
    };

    f32x4 acc[8][4] = {};
    const int NT = K >> 6;
    stage1(0, 0, 0); stage1(0, 0, 1); stage1(0, 0, 2); stage1(0, 0, 3);

    for (int kt = 0; kt < NT; kt++) {
        const int cur = kt & 1;
        const int kn = (kt + 1) << 6;
        const bool pf = (kt + 1 < NT);
        asm volatile("s_waitcnt vmcnt(2)" ::: "memory");   // B0,B1,A0 resident
        __builtin_amdgcn_s_barrier();
        bf16x8 bfr[4][2];
        #pragma unroll
        for (int fj = 0; fj < 4; fj++)
            #pragma unroll
            for (int ks = 0; ks < 2; ks++)
                bfr[fj][ks] = *(const bf16x8*)&LB[cur][wn * 64 + fj * 16 + fr][(ks * 32 + fk) ^ rsw];
        #pragma unroll
        for (int ph = 0; ph < 2; ph++) {
            bf16x8 afr[2][2];
            #pragma unroll
            for (int i2 = 0; i2 < 2; i2++)
                #pragma unroll
                for (int ks = 0; ks < 2; ks++)
                    afr[i2][ks] = *(const bf16x8*)&LA[cur][(ph * 2 + i2) * 32 + wm * 16 + fr][(ks * 32 + fk) ^ rsw];
            if (pf) stage1(cur ^ 1, kn, ph);
            __builtin_amdgcn_s_setprio(1);
            #pragma unroll
            for (int i2 = 0; i2 < 2; i2++)
                #pragma unroll
                for (int ks = 0; ks < 2; ks++)
                    #pragma unroll
                    for (int fj = 0; fj < 4; fj++)
                        acc[ph * 2 + i2][fj] = __builtin_amdgcn_mfma_f32_16x16x32_bf16(
                            afr[i2][ks], bfr[fj][ks], acc[ph * 2 + i2][fj], 0, 0, 0);
            __builtin_amdgcn_s_setprio(0);
        }
        if (pf) asm volatile("s_waitcnt vmcnt(4)" ::: "memory");   // A1 resident
        else    asm volatile("s_waitcnt vmcnt(0)" ::: "memory");
        __builtin_amdgcn_s_barrier();
        #pragma unroll
        for (int ph = 2; ph < 4; ph++) {
            bf16x8 afr[2][2];
            #pragma unroll
            for (int i2 = 0; i2 < 2; i2++)
                #pragma unroll
                for (int ks = 0; ks < 2; ks++)
                    afr[i2][ks] = *(const bf16x8*)&LA[cur][(ph * 2 + i2) * 32 + wm * 16 + fr][(ks * 32 + fk) ^ rsw];
            if (pf) stage1(cur ^ 1, kn, ph);
            __builtin_amdgcn_s_setprio(1);
            #pragma unroll
            for (int i2 = 0; i2 < 2; i2++)
                #pragma unroll
                for (int ks = 0; ks < 2; ks++)
                    #pragma unroll
                    for (int fj = 0; fj < 4; fj++)
                        acc[ph * 2 + i2][fj] = __builtin_amdgcn_mfma_f32_16x16x32_bf16(
                            afr[i2][ks], bfr[fj][ks], acc[ph * 2 + i2][fj], 0, 0, 0);
            __builtin_amdgcn_s_setprio(0);
        }
    }
    const int er = g * 4;
    #pragma unroll
    for (int fi = 0; fi < 8; fi++) {
        #pragma unroll
        for (int reg = 0; reg < 4; reg++) {
            int rr = m0 + fi * 32 + wm * 16 + er + reg;
            #pragma unroll
            for (int fj = 0; fj < 4; fj++) {
                int c = n0 + wn * 64 + fj * 16 + fr;
                float v = acc[fi][fj][reg] + bias[c];
                size_t idx = (size_t)rr * N + c;
                if (MODE == 1) {
                    Cf[idx] += v;
                } else if (MODE == 4) {
                    float nv = Cf[idx] + v;
                    Cf[idx] = nv;
                    Cb[idx] = f2b(nv);
                } else {
                    if (MODE == 2) v = v / (1.0f + expf(-1.702f * v));
                    if (MODE == 3) v = 0.5f * v * (1.0f + erff(v * 0.70710678118654752f));
                    Cb[idx] = f2b(v);
                }
            }
        }
    }
}

// ---- MFMA flash attention v5 (+v_perm P-pack) ---------------------------------
struct FlashP {
    const u16* qp; const u16* kp; const u16* vt; u16* op;
    int Nq, Nk, Nkp, gx, nb;
    long long qA, qI, kA, kJ, oA, oI;
};
__device__ __forceinline__ void flash_body(const FlashP p, int bid,
    u16 (*Ks)[64][64], u16 (*Vs)[64][64], u16 (*Ps)[16][64]) {
    const int x = bid % p.gx, inst = bid / p.gx;
    const int a = inst / 12, h = inst % 12;
    const int tid = threadIdx.x, lane = tid & 63, w = tid >> 6;
    const int fr = lane & 15, g = lane >> 4, fk = g * 8;
    const int f3s = (fr & 7) << 3;
    const u16* qb = p.qp + a * p.qA + h * 64;
    const u16* kb = p.kp + a * p.kA + h * 64;
    const u16* vtb = p.vt + (size_t)inst * 64 * p.Nkp;
    const int q0 = x * 64 + w * 16;

    bf16x8 qf[2];
    {
        u16x8 raw0 = {}, raw1 = {};
        int qr = q0 + fr;
        if (qr < p.Nq) {
            const u16* qrp = qb + (long long)qr * p.qI;
            raw0 = *(const u16x8*)(qrp + fk);
            raw1 = *(const u16x8*)(qrp + 32 + fk);
        }
        const float QS = 0.125f * 1.44269504088896340736f;
        u16x8 s0, s1;
        #pragma unroll
        for (int e = 0; e < 8; e++) {
            s0[e] = f2b(b2f(raw0[e]) * QS);
            s1[e] = f2b(b2f(raw1[e]) * QS);
        }
        qf[0] = *(bf16x8*)&s0;
        qf[1] = *(bf16x8*)&s1;
    }
    float mrun = -1e30f, lrun = 0.f;
    f32x4 o[4] = {};

    const int l = lane;
    const int srow = w * 8 + (l >> 3);
    const int sdcol = ((l & 7) * 8) ^ (((l >> 3) & 7) << 3);

    auto STAGE = [&](int s, int t0) {
        #pragma unroll
        for (int c = 0; c < 2; c++) {
            int row = c * 32 + srow;
            int kr = t0 + row; if (kr >= p.Nk) kr = p.Nk - 1;
            gload16(kb + (long long)kr * p.kJ + sdcol, &Ks[s][0][0] + c * 2048 + w * 512);
            gload16(vtb + (size_t)row * p.Nkp + t0 + sdcol, &Vs[s][0][0] + c * 2048 + w * 512);
        }
    };

    const int nt = (p.Nk + 63) >> 6;
    STAGE(0, 0);
    for (int it = 0; it < nt; ++it) {
        const int t0 = it << 6;
        const int cur = it & 1;
        if (it + 1 < nt) {
            STAGE(cur ^ 1, t0 + 64);
            asm volatile("s_waitcnt vmcnt(4)" ::: "memory");
        } else {
            asm volatile("s_waitcnt vmcnt(0)" ::: "memory");
        }
        __builtin_amdgcn_s_barrier();

        f32x4 s[4] = {};
        __builtin_amdgcn_s_setprio(1);
        #pragma unroll
        for (int hh = 0; hh < 4; hh++) {
            bf16x8 k0f = *(const bf16x8*)&Ks[cur][hh * 16 + fr][fk ^ f3s];
            bf16x8 k1f = *(const bf16x8*)&Ks[cur][hh * 16 + fr][(32 + fk) ^ f3s];
            s[hh] = __builtin_amdgcn_mfma_f32_16x16x32_bf16(k0f, qf[0], s[hh], 0, 0, 0);
            s[hh] = __builtin_amdgcn_mfma_f32_16x16x32_bf16(k1f, qf[1], s[hh], 0, 0, 0);
        }
        __builtin_amdgcn_s_setprio(0);

        if (t0 + 64 > p.Nk) {
            #pragma unroll
            for (int hh = 0; hh < 4; hh++)
                #pragma unroll
                for (int r = 0; r < 4; r++)
                    if (t0 + hh * 16 + 4 * g + r >= p.Nk) s[hh][r] = -1e30f;
        }
        float a0 = fmaxf(fmaxf(s[0][0], s[0][1]), s[0][2]);
        float a1 = fmaxf(fmaxf(s[0][3], s[1][0]), s[1][1]);
        float a2 = fmaxf(fmaxf(s[1][2], s[1][3]), s[2][0]);
        float a3 = fmaxf(fmaxf(s[2][1], s[2][2]), s[2][3]);
        float a4 = fmaxf(fmaxf(s[3][0], s[3][1]), s[3][2]);
        float b0 = fmaxf(fmaxf(a0, a1), a2);
        float b1 = fmaxf(fmaxf(a3, a4), s[3][3]);
        float lmax = fmaxf(b0, b1);
        lmax = fmaxf(lmax, __shfl_xor(lmax, 16, 64));
        lmax = fmaxf(lmax, __shfl_xor(lmax, 32, 64));
        if (!__all(lmax <= mrun + 8.0f)) {            // rescale (rare)
            float mn = fmaxf(mrun, lmax);
            float sf = exp2f(mrun - mn);
            mrun = mn;
            lrun *= sf;
            float sfo[4];
            #pragma unroll
            for (int r = 0; r < 4; r++) sfo[r] = __shfl(sf, g * 4 + r, 64);
            #pragma unroll
            for (int dt = 0; dt < 4; dt++)
                #pragma unroll
                for (int r = 0; r < 4; r++) o[dt][r] *= sfo[r];
        }
        float pp[4][4];
        float ps = 0.f;
        #pragma unroll
        for (int hh = 0; hh < 4; hh++)
            #pragma unroll
            for (int r = 0; r < 4; r++) {
                pp[hh][r] = exp2f(s[hh][r] - mrun);
                ps += pp[hh][r];
            }
        ps += __shfl_xor(ps, 16, 64);
        ps += __shfl_xor(ps, 32, 64);
        lrun += ps;
        // ---- P -> LDS: v_perm packs hi16 of two f32 per op (bit-identical
        // to the previous shift-truncate; P in [0,256] so rel err <= 2^-8) ----
        #pragma unroll
        for (int hh = 0; hh < 4; hh++) {
            u32x2 pk;
            pk[0] = __builtin_amdgcn_perm(fbits(pp[hh][1]), fbits(pp[hh][0]), 0x07060302u);
            pk[1] = __builtin_amdgcn_perm(fbits(pp[hh][3]), fbits(pp[hh][2]), 0x07060302u);
            *(u32x2*)&Ps[w][fr][(hh * 16 + g * 4) ^ f3s] = pk;
        }
        bf16x8 pa0 = *(const bf16x8*)&Ps[w][fr][fk ^ f3s];
        bf16x8 pa1 = *(const bf16x8*)&Ps[w][fr][(32 + fk) ^ f3s];
        __builtin_amdgcn_s_setprio(1);
        #pragma unroll
        for (int dt = 0; dt < 4; dt++) {
            bf16x8 vf0 = *(const bf16x8*)&Vs[cur][dt * 16 + fr][fk ^ f3s];
            bf16x8 vf1 = *(const bf16x8*)&Vs[cur][dt * 16 + fr][(32 + fk) ^ f3s];
            o[dt] = __builtin_amdgcn_mfma_f32_16x16x32_bf16(pa0, vf0, o[dt], 0, 0, 0);
            o[dt] = __builtin_amdgcn_mfma_f32_16x16x32_bf16(pa1, vf1, o[dt], 0, 0, 0);
        }
        __builtin_amdgcn_s_setprio(0);
        __builtin_amdgcn_s_barrier();
    }
    float rcp = 1.0f / lrun;
    #pragma unroll
    for (int r = 0; r < 4; r++) {
        float rr = __shfl(rcp, g * 4 + r, 64);
        int qq = q0 + g * 4 + r;
        if (qq >= p.Nq) continue;
        u16* orow = p.op + a * p.oA + (long long)qq * p.oI + h * 64;
        #pragma unroll
        for (int dt = 0; dt < 4; dt++)
            orow[dt * 16 + fr] = f2b(o[dt][r] * rr);
    }
}
__global__ __launch_bounds__(256) void flash_pair(FlashP p0, FlashP p1) {
    __shared__ u16 Ks[2][64][64];
    __shared__ u16 Vs[2][64][64];
    __shared__ u16 Ps[4][16][64];
    int bid = blockIdx.x;
    if (bid < p0.nb) flash_body(p0, bid, Ks, Vs, Ps);
    else flash_body(p1, bid - p0.nb, Ks, Vs, Ps);
}

// ---------------------------------------------------------------------------
extern "C" void kernel_launch(void* const* d_in, const int* in_sizes, int n_in,
                              void* d_out, int out_size, void* d_ws, size_t ws_size,
                              hipStream_t stream) {
    const int B = 8, sN = 196, tN = 1568;
    const int Ms = B * sN;            // 1568
    const int Mt = B * tN;            // 12544
    const int n_sf = Ms * 768;
    const int n_tf = Mt * 768;
    (void)n_in; (void)out_size; (void)ws_size;

    const bool dict_order = (in_sizes[0] == n_sf);
    auto IN = [&](int di, int ai) -> const float* {
        return (const float*)d_in[dict_order ? di : ai];
    };
    const float* in_sx      = IN(0, 35);
    const float* in_tx      = IN(1, 42);
    const float* ln1s_g     = IN(2, 14);
    const float* ln1s_b     = IN(3, 13);
    const float* mha_w      = IN(4, 28);
    const float* mha_b      = IN(5, 25);
    const float* mha_ow     = IN(6, 27);
    const float* mha_ob     = IN(7, 26);
    const float* ln1t_g     = IN(8, 16);
    const float* ln1t_b     = IN(9, 15);
    const float* attn_qkv_w = IN(10, 3);
    const float* attn_q_b   = IN(11, 2);
    const float* attn_v_b   = IN(12, 4);
    const float* attn_pw    = IN(13, 1);
    const float* attn_pb    = IN(14, 0);
    const float* lnt2s_g    = IN(15, 24);
    const float* lnt2s_b    = IN(16, 23);
    const float* t2s_qw     = IN(17, 41);
    const float* t2s_qb     = IN(18, 40);
    const float* t2s_kvw    = IN(19, 37);
    const float* t2s_kvb    = IN(20, 36);
    const float* t2s_pw     = IN(21, 39);
    const float* t2s_pb     = IN(22, 38);
    const float* lns2t_g    = IN(23, 22);
    const float* lns2t_b    = IN(24, 21);
    const float* s2t_qw     = IN(25, 34);
    const float* s2t_qb     = IN(26, 33);
    const float* s2t_kvw    = IN(27, 30);
    const float* s2t_kvb    = IN(28, 29);
    const float* s2t_pw     = IN(29, 32);
    const float* s2t_pb     = IN(30, 31);
    const float* ln2s_g     = IN(31, 18);
    const float* ln2s_b     = IN(32, 17);
    const float* cfc_w      = IN(33, 6);
    const float* cfc_b      = IN(34, 5);
    const float* cproj_w    = IN(35, 8);
    const float* cproj_b    = IN(36, 7);
    const float* ln2t_g     = IN(37, 20);
    const float* ln2t_b     = IN(38, 19);
    const float* fc1_w      = IN(39, 10);
    const float* fc1_b      = IN(40, 9);
    const float* fc2_w      = IN(41, 12);
    const float* fc2_b      = IN(42, 11);

    float* s_f = (float*)d_out;
    float* t_f = (float*)d_out + n_sf;

    // ---- workspace ----------------------------------------------------------
    char* ws = (char*)d_ws;
    size_t off = 0;
    auto take = [&](size_t bytes) { size_t o = off; off += (bytes + 255) & ~(size_t)255; return o; };
    float* biasP = (float*)(ws + take(19968 * 4));
    u16*   yb    = (u16*)(ws + take((size_t)(Ms + Mt) * 768 * 2));
    u16*   bufA  = (u16*)(ws + take((size_t)Mt * 3072 * 2));
    u16*   bufS  = (u16*)(ws + take((size_t)Mt * 768 * 2));
    u16*   bufB  = (u16*)(ws + take((size_t)Mt * 768 * 2));
    u16*   sxb   = (u16*)(ws + take((size_t)Ms * 768 * 2));
    u16*   vtb_t = (u16*)(ws + take((size_t)96 * 64 * 1600 * 2));
    u16*   yb_s  = yb;
    u16*   yb_t  = yb + (size_t)Ms * 768;
    u16*   vtb_s = yb;   // alias: live only while yb fully dead (steps 6-7)
    auto wtake = [&](size_t nelem) { return (u16*)(ws + take(nelem * 2)); };
    u16 *W_mha   = wtake(2304 * 768), *W_mhao  = wtake(768 * 768);
    u16 *W_qkv   = wtake(2304 * 768), *W_attnp = wtake(768 * 768);
    u16 *W_t2sq  = wtake(768 * 768),  *W_t2skv = wtake(1536 * 768), *W_t2sp = wtake(768 * 768);
    u16 *W_s2tq  = wtake(768 * 768),  *W_s2tkv = wtake(1536 * 768), *W_s2tp = wtake(768 * 768);
    u16 *W_cfc   = wtake(3072 * 768), *W_cproj = wtake(768 * 3072);
    u16 *W_fc1   = wtake(3072 * 768), *W_fc2   = wtake(768 * 3072);

    const int B_MHA = 0, B_QKV = 2304, B_MHAO = 4608, B_ATTNP = 5376;
    const int B_T2SKV = 6144, B_T2SQ = 7680, B_T2SP = 8448, B_S2TQ = 9216;
    const int B_S2TKV = 9984, B_S2TP = 11520, B_CFC = 12288, B_CPROJ = 15360;
    const int B_FC1 = 16128, B_FC2 = 19200;

    auto cdiv = [](int a, int b) { return (a + b - 1) / b; };

    // 1. weights -> bf16
    {
        CvtAll c;
        const float* ss[14] = { mha_w, mha_ow, attn_qkv_w, attn_pw, t2s_qw, t2s_kvw, t2s_pw,
                                s2t_qw, s2t_kvw, s2t_pw, cfc_w, cproj_w, fc1_w, fc2_w };
        u16* dd[14] = { W_mha, W_mhao, W_qkv, W_attnp, W_t2sq, W_t2skv, W_t2sp,
                        W_s2tq, W_s2tkv, W_s2tp, W_cfc, W_cproj, W_fc1, W_fc2 };
        int nn[14] = { 2304*768, 768*768, 2304*768, 768*768, 768*768, 1536*768, 768*768,
                       768*768, 1536*768, 768*768, 3072*768, 768*3072, 3072*768, 768*3072 };
        int cum = 0;
        for (int k = 0; k < 14; k++) { c.s[k] = ss[k]; c.d[k] = dd[k]; c.cum[k] = cum; cum += nn[k]; }
        c.cum[14] = cum;
        cvt_all<<<cdiv(cum, 256), 256, 0, stream>>>(c);
    }
    // 2. bias pool
    build_bias_pool<<<78, 256, 0, stream>>>(biasP,
        mha_b, attn_q_b, attn_v_b, mha_ob, attn_pb, t2s_kvb, t2s_qb, t2s_pb,
        s2t_qb, s2t_kvb, s2t_pb, cfc_b, cproj_b, fc1_b, fc2_b);

    auto GP = [&](const u16* A, const u16* W, const float* bias, u16* Cb, float* Cf,
                  int M, int N, int K, int BM) {
        GemmP p; p.A = A; p.W = W; p.bias = bias; p.Cb = Cb; p.Cf = Cf;
        p.M = M; p.N = N; p.K = K; p.gx = (M + BM - 1) / BM; p.nb = p.gx * (N / 128);
        return p;
    };
    auto ZERO = [&](GemmP p) { GemmP z = p; z.nb = 0; return z; };
    auto FPm = [&](const u16* qp, const u16* kp, const u16* vt, u16* op,
                   int Nq, int Nk, int Nkp, int insts,
                   long long qA, long long qI, long long kA, long long kJ,
                   long long oA, long long oI) {
        FlashP p; p.qp = qp; p.kp = kp; p.vt = vt; p.op = op;
        p.Nq = Nq; p.Nk = Nk; p.Nkp = Nkp; p.gx = (Nq + 63) / 64;
        p.nb = p.gx * insts;
        p.qA = qA; p.qI = qI; p.kA = kA; p.kJ = kJ; p.oA = oA; p.oI = oI;
        return p;
    };
    auto TP = [&](const u16* vp, u16* vt, int Nk, int Nkp, long long vA, long long vJ, int insts) {
        TransP p; p.vp = vp; p.vt = vt; p.Nk = Nk; p.Nkp = Nkp;
        p.gx = (Nk + 63) / 64; p.nb = p.gx * insts; p.vA = vA; p.vJ = vJ;
        return p;
    };

    // 3. stream copy + LN1 pair
    ln_dual_in<<<Ms + Mt, 256, 0, stream>>>(in_sx, in_tx, (float*)d_out, Ms,
        ln1s_g, ln1s_b, yb_s, ln1t_g, ln1t_b, yb_t);

    // 4. qkv_t (256-tile, 441 blocks)
    gemm256<0><<<49 * (2304 / 256), 512, 0, stream>>>(yb_t, W_qkv, biasP + B_QKV, bufA, (float*)0, Mt, 2304, 768);
    // 5. qkv_s (128-tile BM=64, dense)
    {
        GemmP p0 = GP(yb_s, W_mha, biasP + B_MHA, bufS, 0, Ms, 2304, 768, 64);
        gemm_pair<0, 64, 0, 64><<<p0.nb, 256, 0, stream>>>(p0, ZERO(p0));
    }
    // 6. transpose pair
    {
        TransP p0 = TP(bufS + 1536, vtb_s, 8, 64, 2304LL, (long long)sN * 2304, sN * 12);
        TransP p1 = TP(bufA + 1536, vtb_t, tN, 1600, (long long)tN * 2304, 2304LL, B * 12);
        transpose_pair<<<p0.nb + p1.nb, 256, 0, stream>>>(p0, p1);
    }
    // 7. flash pair (stage1 -> sxb, stage2 -> bufB)
    {
        FlashP p0 = FPm(bufS, bufS + 768, vtb_s, sxb, 8, 8, 64, sN * 12,
                        2304LL, (long long)sN * 2304, 2304LL, (long long)sN * 2304,
                        768LL, (long long)sN * 768);
        FlashP p1 = FPm(bufA, bufA + 768, vtb_t, bufB, tN, tN, 1600, B * 12,
                        (long long)tN * 2304, 2304LL, (long long)tN * 2304, 2304LL,
                        (long long)tN * 768, 768LL);
        flash_pair<<<p0.nb + p1.nb, 256, 0, stream>>>(p0, p1);
    }
    // 8. proj pair (mha MODE1 || attn MODE4 -> t_f + yb_t)
    {
        GemmP p0 = GP(sxb, W_mhao, biasP + B_MHAO, 0, s_f, Ms, 768, 768, 64);
        GemmP p1 = GP(bufB, W_attnp, biasP + B_ATTNP, yb_t, t_f, Mt, 768, 768, 128);
        gemm_pair<1, 64, 4, 128><<<p0.nb + p1.nb, 256, 0, stream>>>(p0, p1);
    }
    // 9. LN pair: lnt2s -> yb_s || lns2t -> bufB
    ln_dual<<<Ms + Mt, 256, 0, stream>>>((const float*)d_out, Ms,
        lnt2s_g, lnt2s_b, yb_s, lns2t_g, lns2t_b, bufB);
    // 10. t2s_kv (256-tile, 294 blocks)
    gemm256<0><<<49 * (1536 / 256), 512, 0, stream>>>(yb_t, W_t2skv, biasP + B_T2SKV, bufA, (float*)0, Mt, 1536, 768);
    // 11. s2t_q || t2s_q || transpose(t2s V)
    {
        GemmP p0 = GP(bufB, W_s2tq, biasP + B_S2TQ, bufS, 0, Mt, 768, 768, 128);
        GemmP p1 = GP(yb_s, W_t2sq, biasP + B_T2SQ, sxb, 0, Ms, 768, 768, 64);
        TransP t0 = TP(bufA + 768, vtb_t, tN, 1600, (long long)tN * 1536, 1536LL, B * 12);
        gemm2_trans<0, 128, 0, 64><<<p0.nb + p1.nb + t0.nb, 256, 0, stream>>>(p0, p1, t0);
    }
    // 12. flash stage3 -> yb_s
    {
        FlashP p0 = FPm(sxb, bufA, vtb_t, yb_s, sN, tN, 1600, B * 12,
                        (long long)sN * 768, 768LL, (long long)tN * 1536, 1536LL,
                        (long long)sN * 768, 768LL);
        FlashP pz = p0; pz.nb = 0;
        flash_pair<<<p0.nb, 256, 0, stream>>>(p0, pz);
    }
    // 13. t2s proj (MODE4 -> s_f + sxb mirror)
    {
        GemmP p0 = GP(yb_s, W_t2sp, biasP + B_T2SP, sxb, s_f, Ms, 768, 768, 64);
        gemm_pair<4, 64, 4, 64><<<p0.nb, 256, 0, stream>>>(p0, ZERO(p0));
    }
    // 14. LN ln2s -> yb_s
    ln_dual<<<Ms, 256, 0, stream>>>((const float*)d_out, Ms,
        ln2s_g, ln2s_b, yb_s, ln2s_g, ln2s_b, yb_s);
    // 15. s2t_kv || cfc (QuickGELU -> yb_t)
    {
        GemmP p0 = GP(sxb, W_s2tkv, biasP + B_S2TKV, bufB, 0, Ms, 1536, 768, 64);
        GemmP p1 = GP(yb_s, W_cfc, biasP + B_CFC, yb_t, 0, Ms, 3072, 768, 64);
        gemm_pair<0, 64, 2, 64><<<p0.nb + p1.nb, 256, 0, stream>>>(p0, p1);
    }
    // 16. cproj (MODE1 -> s_f) || transpose(s2t V -> bufA)
    {
        GemmP p0 = GP(yb_t, W_cproj, biasP + B_CPROJ, 0, s_f, Ms, 768, 3072, 64);
        TransP t0 = TP(bufB + 768, bufA, sN, 256, (long long)sN * 1536, 1536LL, B * 12);
        gemm2_trans<1, 64, 1, 64><<<p0.nb + t0.nb, 256, 0, stream>>>(p0, ZERO(p0), t0);
    }
    // 17. flash stage4 -> yb
    {
        FlashP p0 = FPm(bufS, bufB, bufA, yb, tN, sN, 256, B * 12,
                        (long long)tN * 768, 768LL, (long long)sN * 1536, 1536LL,
                        (long long)tN * 768, 768LL);
        FlashP pz = p0; pz.nb = 0;
        flash_pair<<<p0.nb, 256, 0, stream>>>(p0, pz);
    }
    // 18. s2t proj (256-tile, MODE1 -> t_f)
    gemm256<1><<<49 * (768 / 256), 512, 0, stream>>>(yb, W_s2tp, biasP + B_S2TP, (u16*)0, t_f, Mt, 768, 768);
    // 19. LN ln2t -> yb_t
    ln_dual<<<Mt, 256, 0, stream>>>(t_f, 0,
        ln2t_g, ln2t_b, yb_t, ln2t_g, ln2t_b, yb_t);
    // 20. fc1 (256-tile, exact GELU -> bufA, 588 blocks)
    gemm256<3><<<49 * (3072 / 256), 512, 0, stream>>>(yb_t, W_fc1, biasP + B_FC1, bufA, (float*)0, Mt, 3072, 768);
    // 21. fc2 (256-tile, MODE1 -> t_f, K=3072 deep pipeline)
    gemm256<1><<<49 * (768 / 256), 512, 0, stream>>>(bufA, W_fc2, biasP + B_FC2, (u16*)0, t_f, Mt, 768, 3072);
}